// Round 10
// baseline (120.587 us; speedup 1.0000x reference)
//
#include <hip/hip_runtime.h>
#include <hip/hip_bf16.h>
#include <math.h>

#define H_ 14
#define W_ 14
#define HW_ 196
#define CIN_ 1024
#define CMID_ 256
#define NCLS_ 27
#define NB_ 16
#define ROIS_ 980
#define M_ 3136
#define FEAT_ 2304
#define NROI_ (NB_ * ROIS_)   // 15680
#define LROW 2312             // feats LDS row pitch in u16 (+8 pad)

typedef unsigned short u16;
typedef __attribute__((ext_vector_type(8))) short bf16x8;
typedef __attribute__((ext_vector_type(4))) float f32x4;

__device__ __forceinline__ float bf2f(u16 u) {
    union { unsigned int i; float f; } x; x.i = ((unsigned int)u) << 16; return x.f;
}
__device__ __forceinline__ u16 f2bf(float f) {
    __hip_bfloat16 h = __float2bfloat16(f);
    return *reinterpret_cast<u16*>(&h);
}

// ---------------- prep: flat fp32 -> bf16 ----------------
__global__ __launch_bounds__(256) void k_f32_to_bf16(const float* __restrict__ in,
                                                     u16* __restrict__ out) {
    int i = blockIdx.x * 256 + threadIdx.x;
    out[i] = f2bf(in[i]);
}

// ---------------- prep: wfc [27][2304 CHW] -> bf16 [32][2304 bin-major], zero-pad ----------------
__global__ __launch_bounds__(256) void k_prep_wfc(const float* __restrict__ wfc,
                                                  u16* __restrict__ wfcb) {
    int idx = blockIdx.x * 256 + threadIdx.x;       // cls*2304 + k, k = bin*256 + c
    int cls = idx / FEAT_;
    int k = idx - cls * FEAT_;
    int c = k & 255, bin = k >> 8;
    float v = (cls < NCLS_) ? wfc[cls * FEAT_ + c * 9 + bin] : 0.0f;
    wfcb[idx] = f2bf(v);
}

// ---------------- K0: NCHW fp32 -> NHWC bf16, LDS-tiled ----------------
__global__ __launch_bounds__(256) void k_nchw_to_nhwc(const float* __restrict__ in,
                                                      u16* __restrict__ out) {
    __shared__ float lds[64][197];
    const int bid = blockIdx.x;
    const int b = bid >> 4, c0 = (bid & 15) << 6;
    const int t = threadIdx.x;
    const float* src = in + ((size_t)b * CIN_ + c0) * HW_;
    #pragma unroll
    for (int it = 0; it < 49; ++it) {
        int idx = it * 256 + t;
        int ci = idx / 196;
        int hw = idx - ci * 196;
        lds[ci][hw] = src[idx];
    }
    __syncthreads();
    u16* dst = out + (size_t)b * HW_ * CIN_ + c0;
    #pragma unroll
    for (int it = 0; it < 49; ++it) {
        int idx = it * 256 + t;
        int hw = idx >> 6, ci = idx & 63;
        dst[(size_t)hw * CIN_ + ci] = f2bf(lds[ci][hw]);
    }
}

// ---------------- K1: conv1 GEMM 64x64 tile, BK=64, reg-prefetch + BN -> bf16 --------
__global__ __launch_bounds__(256) void k_gemm1(
    const u16* __restrict__ A, const u16* __restrict__ Bw,
    const float* __restrict__ gg, const float* __restrict__ bb,
    const float* __restrict__ mm, const float* __restrict__ vv,
    u16* __restrict__ outp)
{
    __shared__ u16 As[64][72];
    __shared__ u16 Bs[64][72];
    const int bid = blockIdx.x;
    const int swz = (bid & 7) * 98 + (bid >> 3);    // bijective: 784 = 8*98
    const int row0 = (swz >> 4) * 64, col0 = (swz & 15) * 64;
    const int t = threadIdx.x, w = t >> 6, lane = t & 63;
    const int wr = (w >> 1) * 32, wc = (w & 1) * 32;
    const int fr = lane & 15, fk = (lane >> 4) * 8;
    const int sr = t >> 2, sk = (t & 3) * 16;
    f32x4 acc[2][2] = {};

    const u16* Ap = A + (size_t)(row0 + sr) * CIN_ + sk;
    const u16* Bp = Bw + (size_t)(col0 + sr) * CIN_ + sk;
    uint4 a0 = *reinterpret_cast<const uint4*>(Ap);
    uint4 a1 = *reinterpret_cast<const uint4*>(Ap + 8);
    uint4 b0 = *reinterpret_cast<const uint4*>(Bp);
    uint4 b1 = *reinterpret_cast<const uint4*>(Bp + 8);
    for (int kt = 0; kt < 16; ++kt) {
        *reinterpret_cast<uint4*>(&As[sr][sk]) = a0;
        *reinterpret_cast<uint4*>(&As[sr][sk + 8]) = a1;
        *reinterpret_cast<uint4*>(&Bs[sr][sk]) = b0;
        *reinterpret_cast<uint4*>(&Bs[sr][sk + 8]) = b1;
        __syncthreads();
        if (kt < 15) {
            const int k0 = (kt + 1) * 64;
            a0 = *reinterpret_cast<const uint4*>(Ap + k0);
            a1 = *reinterpret_cast<const uint4*>(Ap + k0 + 8);
            b0 = *reinterpret_cast<const uint4*>(Bp + k0);
            b1 = *reinterpret_cast<const uint4*>(Bp + k0 + 8);
        }
        #pragma unroll
        for (int kk = 0; kk < 2; ++kk) {
            const int ko = fk + kk * 32;
            bf16x8 af0 = *reinterpret_cast<bf16x8*>(&As[wr + fr][ko]);
            bf16x8 af1 = *reinterpret_cast<bf16x8*>(&As[wr + 16 + fr][ko]);
            bf16x8 bf0 = *reinterpret_cast<bf16x8*>(&Bs[wc + fr][ko]);
            bf16x8 bf1 = *reinterpret_cast<bf16x8*>(&Bs[wc + 16 + fr][ko]);
            acc[0][0] = __builtin_amdgcn_mfma_f32_16x16x32_bf16(af0, bf0, acc[0][0], 0, 0, 0);
            acc[0][1] = __builtin_amdgcn_mfma_f32_16x16x32_bf16(af0, bf1, acc[0][1], 0, 0, 0);
            acc[1][0] = __builtin_amdgcn_mfma_f32_16x16x32_bf16(af1, bf0, acc[1][0], 0, 0, 0);
            acc[1][1] = __builtin_amdgcn_mfma_f32_16x16x32_bf16(af1, bf1, acc[1][1], 0, 0, 0);
        }
        __syncthreads();
    }
    #pragma unroll
    for (int ni = 0; ni < 2; ++ni) {
        int col = col0 + wc + ni * 16 + fr;
        float sc = gg[col] * rsqrtf(vv[col] + 1e-5f);
        float bi = bb[col] - mm[col] * sc;
        #pragma unroll
        for (int mi = 0; mi < 2; ++mi) {
            #pragma unroll
            for (int rgi = 0; rgi < 4; ++rgi) {
                int row = row0 + wr + mi * 16 + (lane >> 4) * 4 + rgi;
                outp[(size_t)row * CIN_ + col] = f2bf(acc[mi][ni][rgi] * sc + bi);
            }
        }
    }
}

// ---------------- K2: conv2 GEMM (64x64 tile) + BN epilogue ----------------
template<bool OUT_F32>
__global__ __launch_bounds__(256) void k_gemm_bn(
    const u16* __restrict__ A, const u16* __restrict__ Bw,
    const float* __restrict__ gg, const float* __restrict__ bb,
    const float* __restrict__ mm, const float* __restrict__ vv,
    void* __restrict__ outp, int N, int K)
{
    __shared__ u16 As[64][40];
    __shared__ u16 Bs[64][40];
    const int row0 = blockIdx.y * 64, col0 = blockIdx.x * 64;
    const int t = threadIdx.x;
    const int lr = t >> 2, lk = (t & 3) * 8;
    const int wave = t >> 6, lane = t & 63;
    const int wr = (wave >> 1) * 32, wc = (wave & 1) * 32;
    const int fr = lane & 15, fk = (lane >> 4) * 8;
    f32x4 acc[2][2] = {};
    const u16* Aptr = A + (size_t)(row0 + lr) * K + lk;
    const u16* Bptr = Bw + (size_t)(col0 + lr) * K + lk;
    for (int k0 = 0; k0 < K; k0 += 32) {
        *reinterpret_cast<uint4*>(&As[lr][lk]) = *reinterpret_cast<const uint4*>(Aptr + k0);
        *reinterpret_cast<uint4*>(&Bs[lr][lk]) = *reinterpret_cast<const uint4*>(Bptr + k0);
        __syncthreads();
        bf16x8 a0 = *reinterpret_cast<bf16x8*>(&As[wr + fr][fk]);
        bf16x8 a1 = *reinterpret_cast<bf16x8*>(&As[wr + 16 + fr][fk]);
        bf16x8 b0 = *reinterpret_cast<bf16x8*>(&Bs[wc + fr][fk]);
        bf16x8 b1 = *reinterpret_cast<bf16x8*>(&Bs[wc + 16 + fr][fk]);
        acc[0][0] = __builtin_amdgcn_mfma_f32_16x16x32_bf16(a0, b0, acc[0][0], 0, 0, 0);
        acc[0][1] = __builtin_amdgcn_mfma_f32_16x16x32_bf16(a0, b1, acc[0][1], 0, 0, 0);
        acc[1][0] = __builtin_amdgcn_mfma_f32_16x16x32_bf16(a1, b0, acc[1][0], 0, 0, 0);
        acc[1][1] = __builtin_amdgcn_mfma_f32_16x16x32_bf16(a1, b1, acc[1][1], 0, 0, 0);
        __syncthreads();
    }
    #pragma unroll
    for (int ni = 0; ni < 2; ++ni) {
        int col = col0 + wc + ni * 16 + fr;
        float sc = gg[col] * rsqrtf(vv[col] + 1e-5f);
        float bi = bb[col] - mm[col] * sc;
        #pragma unroll
        for (int mi = 0; mi < 2; ++mi) {
            #pragma unroll
            for (int rgi = 0; rgi < 4; ++rgi) {
                int row = row0 + wr + mi * 16 + (lane >> 4) * 4 + rgi;
                float v = acc[mi][ni][rgi] * sc + bi;
                if (OUT_F32) ((float*)outp)[(size_t)row * N + col] = v;
                else         ((u16*)outp)[(size_t)row * N + col] = f2bf(v);
            }
        }
    }
}

// ---------------- K3: FUSED roi_align + FC ----------------
// Block = 16 rois, 4 waves. Phase 1: each wave pools 4 rois (separable-window,
// f32x4/lane = 4 channels) -> bf16 feats in LDS [16][LROW]. Phase 2: FC via MFMA,
// A-rows = 16 rois from LDS, B = wfcb (L2-hot), each wave owns a 576-wide K-quarter.
// Phase 3: cross-wave reduce via LDS scratch (aliased over consumed feats), +bias.
__global__ __launch_bounds__(256) void k_roi_fc(
    const float* __restrict__ boxes, const float* __restrict__ fmap,
    const u16* __restrict__ wfcb, const float* __restrict__ bfc,
    float* __restrict__ out)
{
    __shared__ u16 lbuf[16 * LROW];    // 73,984 B
    const int t = threadIdx.x, w = t >> 6, lane = t & 63;
    const int r0 = blockIdx.x * 16;
    const float OFFS[6] = {0.25f, 0.75f, 1.25f, 1.75f, 2.25f, 2.75f};

    // ---- phase 1: roi_align, 4 rois per wave ----
    for (int ri = w; ri < 16; ri += 4) {
        const int r = r0 + ri;
        const int b = r / ROIS_;
        const float* bxp = boxes + (size_t)r * 4;
        float x1 = bxp[0], y1 = bxp[1];
        float rw = fmaxf(bxp[2] - x1, 1.0f), rh = fmaxf(bxp[3] - y1, 1.0f);
        float sx = rw * (1.0f / 3.0f), sy = rh * (1.0f / 3.0f);
        int xl[6], xh[6], yl[6], yh[6];
        float lx[6], hx[6], ly[6], hy[6];
        #pragma unroll
        for (int i = 0; i < 6; ++i) {
            float xx = fmaxf(x1 + OFFS[i] * sx, 0.0f);
            xl[i] = min((int)xx, 13); xh[i] = min(xl[i] + 1, 13);
            float xv = (xl[i] == 13) ? 13.0f : xx;
            lx[i] = xv - (float)xl[i]; hx[i] = 1.0f - lx[i];
            float yy = fmaxf(y1 + OFFS[i] * sy, 0.0f);
            yl[i] = min((int)yy, 13); yh[i] = min(yl[i] + 1, 13);
            float yv = (yl[i] == 13) ? 13.0f : yy;
            ly[i] = yv - (float)yl[i]; hy[i] = 1.0f - ly[i];
        }
        const int xc0 = min(xl[0], 8), yr0 = min(yl[0], 8);
        float WX[3][6], WY[3][6];
        #pragma unroll
        for (int bi = 0; bi < 3; ++bi)
            #pragma unroll
            for (int c = 0; c < 6; ++c) { WX[bi][c] = 0.0f; WY[bi][c] = 0.0f; }
        #pragma unroll
        for (int i = 0; i < 6; ++i) {
            const int bi = i >> 1;
            #pragma unroll
            for (int c = 0; c < 6; ++c) {
                WX[bi][c] += (xl[i] - xc0 == c ? hx[i] : 0.0f)
                           + (xh[i] - xc0 == c ? lx[i] : 0.0f);
                WY[bi][c] += (yl[i] - yr0 == c ? hy[i] : 0.0f)
                           + (yh[i] - yr0 == c ? ly[i] : 0.0f);
            }
        }
        const float* base = fmap + ((size_t)b * HW_ + yr0 * 14 + xc0) * CMID_ + lane * 4;
        f32x4 pooled[3][3] = {};
        #pragma unroll
        for (int rr = 0; rr < 6; ++rr) {
            const float* rp = base + rr * (14 * CMID_);
            f32x4 P[6];
            #pragma unroll
            for (int c = 0; c < 6; ++c)
                P[c] = *reinterpret_cast<const f32x4*>(rp + c * CMID_);
            f32x4 xin[3] = {};
            #pragma unroll
            for (int c = 0; c < 6; ++c) {
                #pragma unroll
                for (int bxx = 0; bxx < 3; ++bxx)
                    xin[bxx] += P[c] * WX[bxx][c];
            }
            #pragma unroll
            for (int by = 0; by < 3; ++by)
                #pragma unroll
                for (int bxx = 0; bxx < 3; ++bxx)
                    pooled[by][bxx] += xin[bxx] * WY[by][rr];
        }
        u16* fo = lbuf + ri * LROW + lane * 4;
        #pragma unroll
        for (int by = 0; by < 3; ++by) {
            #pragma unroll
            for (int bxx = 0; bxx < 3; ++bxx) {
                const int bin = by * 3 + bxx;
                f32x4 p = pooled[by][bxx] * 0.25f;
                ushort4 s;
                s.x = f2bf(p[0]); s.y = f2bf(p[1]); s.z = f2bf(p[2]); s.w = f2bf(p[3]);
                *reinterpret_cast<ushort4*>(fo + bin * 256) = s;
            }
        }
    }
    __syncthreads();

    // ---- phase 2: FC MFMA, wave w owns K in [w*576, w*576+576) ----
    const int fr = lane & 15, fkq = (lane >> 4) * 8;
    f32x4 acc[2] = {};
    const int kbase = w * 576;
    for (int ks = 0; ks < 18; ++ks) {
        const int k0 = kbase + ks * 32 + fkq;
        bf16x8 a  = *reinterpret_cast<bf16x8*>(&lbuf[fr * LROW + k0]);
        bf16x8 b0 = *reinterpret_cast<const bf16x8*>(wfcb + (size_t)fr * FEAT_ + k0);
        bf16x8 b1 = *reinterpret_cast<const bf16x8*>(wfcb + (size_t)(16 + fr) * FEAT_ + k0);
        acc[0] = __builtin_amdgcn_mfma_f32_16x16x32_bf16(a, b0, acc[0], 0, 0, 0);
        acc[1] = __builtin_amdgcn_mfma_f32_16x16x32_bf16(a, b1, acc[1], 0, 0, 0);
    }
    __syncthreads();   // all waves done reading lbuf

    // ---- phase 3: cross-wave reduce via scratch aliased on lbuf ----
    float* sc = (float*)lbuf;          // 4*16*32 floats = 8 KB
    #pragma unroll
    for (int ni = 0; ni < 2; ++ni)
        #pragma unroll
        for (int rg = 0; rg < 4; ++rg)
            sc[w * 512 + ((lane >> 4) * 4 + rg) * 32 + ni * 16 + fr] = acc[ni][rg];
    __syncthreads();
    #pragma unroll
    for (int o = t; o < 512; o += 256) {
        int roi = o >> 5, cls = o & 31;
        if (cls < NCLS_) {
            float s = sc[o] + sc[512 + o] + sc[1024 + o] + sc[1536 + o];
            out[(size_t)(r0 + roi) * NCLS_ + cls] = s + bfc[cls];
        }
    }
}

extern "C" void kernel_launch(void* const* d_in, const int* in_sizes, int n_in,
                              void* d_out, int out_size, void* d_ws, size_t ws_size,
                              hipStream_t stream) {
    const float* boxes   = (const float*)d_in[0];
    const float* fmap_in = (const float*)d_in[1];
    const float* w1 = (const float*)d_in[2];
    const float* g1 = (const float*)d_in[3];
    const float* b1 = (const float*)d_in[4];
    const float* m1 = (const float*)d_in[5];
    const float* v1 = (const float*)d_in[6];
    const float* w2 = (const float*)d_in[7];
    const float* g2 = (const float*)d_in[8];
    const float* b2 = (const float*)d_in[9];
    const float* m2 = (const float*)d_in[10];
    const float* v2 = (const float*)d_in[11];
    const float* wfc = (const float*)d_in[12];
    const float* bfc = (const float*)d_in[13];

    char* ws = (char*)d_ws;
    u16*   Anhwc     = (u16*)(ws + 0);               //  6,422,528 B
    float* fmapw_f32 = (float*)(ws + 0);             //  aliases Anhwc (dead after conv1)
    u16*   h         = (u16*)(ws + 6422528);         //  6,422,528 B
    u16*   w1b       = (u16*)(ws + 14450688);        //  2,097,152 B
    u16*   w2b       = (u16*)(ws + 16547840);        //    524,288 B
    u16*   wfcb      = (u16*)(ws + 17072128);        //    147,456 B

    hipLaunchKernelGGL(k_f32_to_bf16, dim3((CIN_ * CIN_) / 256), dim3(256), 0, stream,
                       w1, w1b);
    hipLaunchKernelGGL(k_f32_to_bf16, dim3((CMID_ * CIN_) / 256), dim3(256), 0, stream,
                       w2, w2b);
    hipLaunchKernelGGL(k_prep_wfc, dim3((32 * FEAT_) / 256), dim3(256), 0, stream,
                       wfc, wfcb);
    hipLaunchKernelGGL(k_nchw_to_nhwc, dim3(NB_ * 16), dim3(256), 0, stream,
                       fmap_in, Anhwc);
    hipLaunchKernelGGL(k_gemm1, dim3(784), dim3(256), 0, stream,
                       Anhwc, w1b, g1, b1, m1, v1, h);
    hipLaunchKernelGGL((k_gemm_bn<true>), dim3(CMID_ / 64, M_ / 64), dim3(256), 0, stream,
                       h, w2b, g2, b2, m2, v2, (void*)fmapw_f32, CMID_, CIN_);
    hipLaunchKernelGGL(k_roi_fc, dim3(NROI_ / 16), dim3(256), 0, stream,
                       boxes, fmapw_f32, wfcb, bfc, (float*)d_out);
}

// Round 11
// 96.337 us; speedup vs baseline: 1.2517x; 1.2517x over previous
//
#include <hip/hip_runtime.h>
#include <hip/hip_bf16.h>
#include <math.h>

#define H_ 14
#define W_ 14
#define HW_ 196
#define CIN_ 1024
#define CMID_ 256
#define NCLS_ 27
#define NB_ 16
#define ROIS_ 980
#define M_ 3136
#define FEAT_ 2304
#define NROI_ (NB_ * ROIS_)   // 15680
#define NCB_ 256              // padded cb = cls*9+bin (243 real)

typedef unsigned short u16;
typedef __attribute__((ext_vector_type(8))) short bf16x8;
typedef __attribute__((ext_vector_type(4))) float f32x4;

__device__ __forceinline__ float bf2f(u16 u) {
    union { unsigned int i; float f; } x; x.i = ((unsigned int)u) << 16; return x.f;
}
__device__ __forceinline__ u16 f2bf(float f) {
    __hip_bfloat16 h = __float2bfloat16(f);
    return *reinterpret_cast<u16*>(&h);
}

// ---------------- prep: flat fp32 -> bf16 ----------------
__global__ __launch_bounds__(256) void k_f32_to_bf16(const float* __restrict__ in,
                                                     u16* __restrict__ out) {
    int i = blockIdx.x * 256 + threadIdx.x;
    out[i] = f2bf(in[i]);
}

// ---------------- prep: w_bin[cb][c] = wfc[cls][c*9+bin] bf16, zero-pad cb>=243 ------
__global__ __launch_bounds__(256) void k_prep_wbin(const float* __restrict__ wfc,
                                                   u16* __restrict__ w_bin) {
    int idx = blockIdx.x * 256 + threadIdx.x;      // cb*256 + c
    int cb = idx >> 8, c = idx & 255;
    int cls = cb / 9, bin = cb - cls * 9;
    float v = (cb < 243) ? wfc[cls * FEAT_ + c * 9 + bin] : 0.0f;
    w_bin[idx] = f2bf(v);
}

// ---------------- prep: w2s[k][c] = w2[c][k] * sc2[c], bf16 (LDS-tiled transpose) ----
__global__ __launch_bounds__(256) void k_prep_w2s(const float* __restrict__ w2,
                                                  const float* __restrict__ g2,
                                                  const float* __restrict__ v2,
                                                  u16* __restrict__ w2s) {
    __shared__ float ld[64][65];
    const int kt = blockIdx.x & 15, ct = blockIdx.x >> 4;
    const int t = threadIdx.x, rr = t >> 6, cc = t & 63;
    #pragma unroll
    for (int it = 0; it < 16; ++it) {
        int row = it * 4 + rr;   // c within tile
        ld[row][cc] = w2[(size_t)(ct * 64 + row) * CIN_ + kt * 64 + cc];
    }
    __syncthreads();
    float sc = g2[ct * 64 + cc] * rsqrtf(v2[ct * 64 + cc] + 1e-5f);
    #pragma unroll
    for (int it = 0; it < 16; ++it) {
        int krow = it * 4 + rr;  // k within tile
        w2s[(size_t)(kt * 64 + krow) * CMID_ + ct * 64 + cc] = f2bf(ld[cc][krow] * sc);
    }
}

// ---------------- prep: cfc[cls] = bfc[cls] + sum_bin sum_c w_bin[cb][c]*bi2[c] ------
__global__ __launch_bounds__(256) void k_cfc(const u16* __restrict__ w_bin,
                                             const float* __restrict__ g2,
                                             const float* __restrict__ b2,
                                             const float* __restrict__ m2,
                                             const float* __restrict__ v2,
                                             const float* __restrict__ bfc,
                                             float* __restrict__ cfc) {
    __shared__ float bi2[256];
    __shared__ float part[256];
    const int t = threadIdx.x;
    bi2[t] = b2[t] - m2[t] * (g2[t] * rsqrtf(v2[t] + 1e-5f));
    __syncthreads();
    float s = 0.0f;
    for (int c = 0; c < 256; ++c) s += bf2f(w_bin[t * 256 + c]) * bi2[c];
    part[t] = s;
    __syncthreads();
    if (t < NCLS_) {
        float acc = bfc[t];
        #pragma unroll
        for (int bin = 0; bin < 9; ++bin) acc += part[t * 9 + bin];
        cfc[t] = acc;
    }
}

// ---------------- K0: NCHW fp32 -> NHWC bf16, LDS-tiled ----------------
__global__ __launch_bounds__(256) void k_nchw_to_nhwc(const float* __restrict__ in,
                                                      u16* __restrict__ out) {
    __shared__ float lds[64][197];
    const int bid = blockIdx.x;
    const int b = bid >> 4, c0 = (bid & 15) << 6;
    const int t = threadIdx.x;
    const float* src = in + ((size_t)b * CIN_ + c0) * HW_;
    #pragma unroll
    for (int it = 0; it < 49; ++it) {
        int idx = it * 256 + t;
        int ci = idx / 196;
        int hw = idx - ci * 196;
        lds[ci][hw] = src[idx];
    }
    __syncthreads();
    u16* dst = out + (size_t)b * HW_ * CIN_ + c0;
    #pragma unroll
    for (int it = 0; it < 49; ++it) {
        int idx = it * 256 + t;
        int hw = idx >> 6, ci = idx & 63;
        dst[(size_t)hw * CIN_ + ci] = f2bf(lds[ci][hw]);
    }
}

// ---------------- K1: conv1 GEMM 64x64 tile, BK=64, reg-prefetch + BN -> bf16 --------
__global__ __launch_bounds__(256) void k_gemm1(
    const u16* __restrict__ A, const u16* __restrict__ Bw,
    const float* __restrict__ gg, const float* __restrict__ bb,
    const float* __restrict__ mm, const float* __restrict__ vv,
    u16* __restrict__ outp)
{
    __shared__ u16 As[64][72];
    __shared__ u16 Bs[64][72];
    const int bid = blockIdx.x;
    const int swz = (bid & 7) * 98 + (bid >> 3);    // bijective: 784 = 8*98
    const int row0 = (swz >> 4) * 64, col0 = (swz & 15) * 64;
    const int t = threadIdx.x, w = t >> 6, lane = t & 63;
    const int wr = (w >> 1) * 32, wc = (w & 1) * 32;
    const int fr = lane & 15, fk = (lane >> 4) * 8;
    const int sr = t >> 2, sk = (t & 3) * 16;
    f32x4 acc[2][2] = {};

    const u16* Ap = A + (size_t)(row0 + sr) * CIN_ + sk;
    const u16* Bp = Bw + (size_t)(col0 + sr) * CIN_ + sk;
    uint4 a0 = *reinterpret_cast<const uint4*>(Ap);
    uint4 a1 = *reinterpret_cast<const uint4*>(Ap + 8);
    uint4 b0 = *reinterpret_cast<const uint4*>(Bp);
    uint4 b1 = *reinterpret_cast<const uint4*>(Bp + 8);
    for (int kt = 0; kt < 16; ++kt) {
        *reinterpret_cast<uint4*>(&As[sr][sk]) = a0;
        *reinterpret_cast<uint4*>(&As[sr][sk + 8]) = a1;
        *reinterpret_cast<uint4*>(&Bs[sr][sk]) = b0;
        *reinterpret_cast<uint4*>(&Bs[sr][sk + 8]) = b1;
        __syncthreads();
        if (kt < 15) {
            const int k0 = (kt + 1) * 64;
            a0 = *reinterpret_cast<const uint4*>(Ap + k0);
            a1 = *reinterpret_cast<const uint4*>(Ap + k0 + 8);
            b0 = *reinterpret_cast<const uint4*>(Bp + k0);
            b1 = *reinterpret_cast<const uint4*>(Bp + k0 + 8);
        }
        #pragma unroll
        for (int kk = 0; kk < 2; ++kk) {
            const int ko = fk + kk * 32;
            bf16x8 af0 = *reinterpret_cast<bf16x8*>(&As[wr + fr][ko]);
            bf16x8 af1 = *reinterpret_cast<bf16x8*>(&As[wr + 16 + fr][ko]);
            bf16x8 bf0 = *reinterpret_cast<bf16x8*>(&Bs[wc + fr][ko]);
            bf16x8 bf1 = *reinterpret_cast<bf16x8*>(&Bs[wc + 16 + fr][ko]);
            acc[0][0] = __builtin_amdgcn_mfma_f32_16x16x32_bf16(af0, bf0, acc[0][0], 0, 0, 0);
            acc[0][1] = __builtin_amdgcn_mfma_f32_16x16x32_bf16(af0, bf1, acc[0][1], 0, 0, 0);
            acc[1][0] = __builtin_amdgcn_mfma_f32_16x16x32_bf16(af1, bf0, acc[1][0], 0, 0, 0);
            acc[1][1] = __builtin_amdgcn_mfma_f32_16x16x32_bf16(af1, bf1, acc[1][1], 0, 0, 0);
        }
        __syncthreads();
    }
    #pragma unroll
    for (int ni = 0; ni < 2; ++ni) {
        int col = col0 + wc + ni * 16 + fr;
        float sc = gg[col] * rsqrtf(vv[col] + 1e-5f);
        float bi = bb[col] - mm[col] * sc;
        #pragma unroll
        for (int mi = 0; mi < 2; ++mi) {
            #pragma unroll
            for (int rgi = 0; rgi < 4; ++rgi) {
                int row = row0 + wr + mi * 16 + (lane >> 4) * 4 + rgi;
                outp[(size_t)row * CIN_ + col] = f2bf(acc[mi][ni][rgi] * sc + bi);
            }
        }
    }
}

// ---------------- K2: generic GEMM (64x64 tile), optional BN, bf16/f32 out ----------
template<bool OUT_F32, bool BN>
__global__ __launch_bounds__(256) void k_gemm_bn(
    const u16* __restrict__ A, const u16* __restrict__ Bw,
    const float* __restrict__ gg, const float* __restrict__ bb,
    const float* __restrict__ mm, const float* __restrict__ vv,
    void* __restrict__ outp, int N, int K)
{
    __shared__ u16 As[64][40];
    __shared__ u16 Bs[64][40];
    const int row0 = blockIdx.y * 64, col0 = blockIdx.x * 64;
    const int t = threadIdx.x;
    const int lr = t >> 2, lk = (t & 3) * 8;
    const int wave = t >> 6, lane = t & 63;
    const int wr = (wave >> 1) * 32, wc = (wave & 1) * 32;
    const int fr = lane & 15, fk = (lane >> 4) * 8;
    f32x4 acc[2][2] = {};
    const u16* Aptr = A + (size_t)(row0 + lr) * K + lk;
    const u16* Bptr = Bw + (size_t)(col0 + lr) * K + lk;
    for (int k0 = 0; k0 < K; k0 += 32) {
        *reinterpret_cast<uint4*>(&As[lr][lk]) = *reinterpret_cast<const uint4*>(Aptr + k0);
        *reinterpret_cast<uint4*>(&Bs[lr][lk]) = *reinterpret_cast<const uint4*>(Bptr + k0);
        __syncthreads();
        bf16x8 a0 = *reinterpret_cast<bf16x8*>(&As[wr + fr][fk]);
        bf16x8 a1 = *reinterpret_cast<bf16x8*>(&As[wr + 16 + fr][fk]);
        bf16x8 b0 = *reinterpret_cast<bf16x8*>(&Bs[wc + fr][fk]);
        bf16x8 b1 = *reinterpret_cast<bf16x8*>(&Bs[wc + 16 + fr][fk]);
        acc[0][0] = __builtin_amdgcn_mfma_f32_16x16x32_bf16(a0, b0, acc[0][0], 0, 0, 0);
        acc[0][1] = __builtin_amdgcn_mfma_f32_16x16x32_bf16(a0, b1, acc[0][1], 0, 0, 0);
        acc[1][0] = __builtin_amdgcn_mfma_f32_16x16x32_bf16(a1, b0, acc[1][0], 0, 0, 0);
        acc[1][1] = __builtin_amdgcn_mfma_f32_16x16x32_bf16(a1, b1, acc[1][1], 0, 0, 0);
        __syncthreads();
    }
    #pragma unroll
    for (int ni = 0; ni < 2; ++ni) {
        int col = col0 + wc + ni * 16 + fr;
        float sc = 1.0f, bi = 0.0f;
        if (BN) {
            sc = gg[col] * rsqrtf(vv[col] + 1e-5f);
            bi = bb[col] - mm[col] * sc;
        }
        #pragma unroll
        for (int mi = 0; mi < 2; ++mi) {
            #pragma unroll
            for (int rgi = 0; rgi < 4; ++rgi) {
                int row = row0 + wr + mi * 16 + (lane >> 4) * 4 + rgi;
                float v = BN ? (acc[mi][ni][rgi] * sc + bi) : acc[mi][ni][rgi];
                if (OUT_F32) ((float*)outp)[(size_t)row * N + col] = v;
                else         ((u16*)outp)[(size_t)row * N + col] = f2bf(v);
            }
        }
    }
}

// ---------------- K3: roi pooling on G -> logits directly ----------------
// One WAVE per roi. Lane owns 4 cb columns (cb = cls*9+bin, padded 256). Separable
// window weights as in R7; per-cb (by,bx) selected once into wx4/wy4 vectors.
// pooled_cb = 0.25 * sum_rr WY . sum_cc WX . G[window]. Bin-sum via tiny LDS.
__global__ __launch_bounds__(256) void k_roi_logits(
    const float* __restrict__ boxes, const float* __restrict__ G,
    const float* __restrict__ cfc, float* __restrict__ out)
{
    __shared__ float sred[4][260];
    const int t = threadIdx.x, w = t >> 6, lane = t & 63;
    const int r = blockIdx.x * 4 + w;
    const int b = r / ROIS_;
    const float* bxp = boxes + (size_t)r * 4;
    float x1 = bxp[0], y1 = bxp[1];
    float rw = fmaxf(bxp[2] - x1, 1.0f), rh = fmaxf(bxp[3] - y1, 1.0f);
    float sx = rw * (1.0f / 3.0f), sy = rh * (1.0f / 3.0f);
    const float OFFS[6] = {0.25f, 0.75f, 1.25f, 1.75f, 2.25f, 2.75f};

    int xl[6], xh[6], yl[6], yh[6];
    float lx[6], hx[6], ly[6], hy[6];
    #pragma unroll
    for (int i = 0; i < 6; ++i) {
        float xx = fmaxf(x1 + OFFS[i] * sx, 0.0f);
        xl[i] = min((int)xx, 13); xh[i] = min(xl[i] + 1, 13);
        float xv = (xl[i] == 13) ? 13.0f : xx;
        lx[i] = xv - (float)xl[i]; hx[i] = 1.0f - lx[i];
        float yy = fmaxf(y1 + OFFS[i] * sy, 0.0f);
        yl[i] = min((int)yy, 13); yh[i] = min(yl[i] + 1, 13);
        float yv = (yl[i] == 13) ? 13.0f : yy;
        ly[i] = yv - (float)yl[i]; hy[i] = 1.0f - ly[i];
    }
    const int xc0 = min(xl[0], 8), yr0 = min(yl[0], 8);

    float WX[3][6], WY[3][6];
    #pragma unroll
    for (int bi = 0; bi < 3; ++bi)
        #pragma unroll
        for (int c = 0; c < 6; ++c) { WX[bi][c] = 0.0f; WY[bi][c] = 0.0f; }
    #pragma unroll
    for (int i = 0; i < 6; ++i) {
        const int bi = i >> 1;
        #pragma unroll
        for (int c = 0; c < 6; ++c) {
            WX[bi][c] += (xl[i] - xc0 == c ? hx[i] : 0.0f)
                       + (xh[i] - xc0 == c ? lx[i] : 0.0f);
            WY[bi][c] += (yl[i] - yr0 == c ? hy[i] : 0.0f)
                       + (yh[i] - yr0 == c ? ly[i] : 0.0f);
        }
    }

    // per-lane cb meta -> per-element weight vectors (static selects only)
    int bxj[4], byj[4];
    #pragma unroll
    for (int j = 0; j < 4; ++j) {
        int cb = lane * 4 + j;
        int cls = cb / 9;
        int bin = cb - cls * 9;
        bxj[j] = bin % 3; byj[j] = bin / 3;
    }
    f32x4 wx4[6], wy4[6];
    #pragma unroll
    for (int q = 0; q < 6; ++q) {
        #pragma unroll
        for (int j = 0; j < 4; ++j) {
            wx4[q][j] = (bxj[j] == 0) ? WX[0][q] : ((bxj[j] == 1) ? WX[1][q] : WX[2][q]);
            wy4[q][j] = (byj[j] == 0) ? WY[0][q] : ((byj[j] == 1) ? WY[1][q] : WY[2][q]);
        }
    }

    const float* base = G + ((size_t)b * HW_ + yr0 * 14 + xc0) * NCB_ + lane * 4;
    f32x4 acc = {};
    #pragma unroll
    for (int rr = 0; rr < 6; ++rr) {
        const float* rp = base + rr * (14 * NCB_);
        f32x4 tmp = {};
        #pragma unroll
        for (int cc = 0; cc < 6; ++cc) {
            f32x4 g = *reinterpret_cast<const f32x4*>(rp + cc * NCB_);
            tmp += g * wx4[cc];
        }
        acc += tmp * wy4[rr];
    }
    acc *= 0.25f;
    #pragma unroll
    for (int j = 0; j < 4; ++j) sred[w][lane * 4 + j] = acc[j];
    __syncthreads();
    if (lane < NCLS_) {
        float s = cfc[lane];
        #pragma unroll
        for (int bin = 0; bin < 9; ++bin) s += sred[w][lane * 9 + bin];
        out[(size_t)r * NCLS_ + lane] = s;
    }
}

extern "C" void kernel_launch(void* const* d_in, const int* in_sizes, int n_in,
                              void* d_out, int out_size, void* d_ws, size_t ws_size,
                              hipStream_t stream) {
    const float* boxes   = (const float*)d_in[0];
    const float* fmap_in = (const float*)d_in[1];
    const float* w1 = (const float*)d_in[2];
    const float* g1 = (const float*)d_in[3];
    const float* b1 = (const float*)d_in[4];
    const float* m1 = (const float*)d_in[5];
    const float* v1 = (const float*)d_in[6];
    const float* w2 = (const float*)d_in[7];
    const float* g2 = (const float*)d_in[8];
    const float* b2 = (const float*)d_in[9];
    const float* m2 = (const float*)d_in[10];
    const float* v2 = (const float*)d_in[11];
    const float* wfc = (const float*)d_in[12];
    const float* bfc = (const float*)d_in[13];

    char* ws = (char*)d_ws;
    u16*   Anhwc = (u16*)(ws + 0);                   // 6,422,528 B
    float* G     = (float*)(ws + 0);                 // 3,211,264 B (aliases Anhwc; dead after gemm1)
    u16*   h     = (u16*)(ws + 6422528);             // 6,422,528 B
    u16*   w1b   = (u16*)(ws + 14450688);            // 2,097,152 B
    u16*   w_bin = (u16*)(ws + 16547840);            //   131,072 B
    u16*   w2s   = (u16*)(ws + 16678912);            //   524,288 B
    u16*   wG    = (u16*)(ws + 17203200);            //   524,288 B
    float* cfc   = (float*)(ws + 17727488);          //       128 B

    hipLaunchKernelGGL(k_f32_to_bf16, dim3((CIN_ * CIN_) / 256), dim3(256), 0, stream,
                       w1, w1b);
    hipLaunchKernelGGL(k_prep_wbin, dim3((NCB_ * 256) / 256), dim3(256), 0, stream,
                       wfc, w_bin);
    hipLaunchKernelGGL(k_prep_w2s, dim3(64), dim3(256), 0, stream,
                       w2, g2, v2, w2s);
    // wG[cb][k] = sum_c w_bin[cb][c] * w2s[k][c]   (M=256, N=1024, K=256) -> bf16
    hipLaunchKernelGGL((k_gemm_bn<false, false>), dim3(CIN_ / 64, NCB_ / 64), dim3(256),
                       0, stream, w_bin, w2s, nullptr, nullptr, nullptr, nullptr,
                       (void*)wG, CIN_, CMID_);
    hipLaunchKernelGGL(k_cfc, dim3(1), dim3(256), 0, stream,
                       w_bin, g2, b2, m2, v2, bfc, cfc);
    hipLaunchKernelGGL(k_nchw_to_nhwc, dim3(NB_ * 16), dim3(256), 0, stream,
                       fmap_in, Anhwc);
    hipLaunchKernelGGL(k_gemm1, dim3(784), dim3(256), 0, stream,
                       Anhwc, w1b, g1, b1, m1, v1, h);
    // G = h * wG^T  (M=3136, N=256, K=1024) -> fp32 (replaces conv2 AND the FC)
    hipLaunchKernelGGL((k_gemm_bn<true, false>), dim3(NCB_ / 64, M_ / 64), dim3(256),
                       0, stream, h, wG, nullptr, nullptr, nullptr, nullptr,
                       (void*)G, NCB_, CIN_);
    hipLaunchKernelGGL(k_roi_logits, dim3(NROI_ / 4), dim3(256), 0, stream,
                       boxes, G, cfc, (float*)d_out);
}

// Round 12
// 85.181 us; speedup vs baseline: 1.4157x; 1.1310x over previous
//
#include <hip/hip_runtime.h>
#include <hip/hip_bf16.h>
#include <math.h>

#define H_ 14
#define W_ 14
#define HW_ 196
#define CIN_ 1024
#define CMID_ 256
#define NCLS_ 27
#define NB_ 16
#define ROIS_ 980
#define M_ 3136
#define FEAT_ 2304
#define NROI_ (NB_ * ROIS_)   // 15680
#define NCB_ 256              // padded cb = cls*9+bin (243 real)

typedef unsigned short u16;
typedef __attribute__((ext_vector_type(8))) short bf16x8;
typedef __attribute__((ext_vector_type(4))) float f32x4;

__device__ __forceinline__ float bf2f(u16 u) {
    union { unsigned int i; float f; } x; x.i = ((unsigned int)u) << 16; return x.f;
}
__device__ __forceinline__ float bits2f(unsigned int u) {
    union { unsigned int i; float f; } x; x.i = u; return x.f;
}
__device__ __forceinline__ u16 f2bf(float f) {
    __hip_bfloat16 h = __float2bfloat16(f);
    return *reinterpret_cast<u16*>(&h);
}

// ---------------- merged prep: w1 cast | w_bin permute | w2s transpose+scale --------
__global__ __launch_bounds__(256) void k_prep(
    const float* __restrict__ w1, u16* __restrict__ w1b,
    const float* __restrict__ wfc, u16* __restrict__ w_bin,
    const float* __restrict__ w2, const float* __restrict__ g2,
    const float* __restrict__ v2, u16* __restrict__ w2s)
{
    __shared__ float ld[64][65];
    const int bid = blockIdx.x, t = threadIdx.x;
    if (bid < 4096) {                      // w1 -> bf16
        int i = bid * 256 + t;
        w1b[i] = f2bf(w1[i]);
        return;
    }
    if (bid < 4096 + 256) {                // w_bin[cb][c] = wfc[cls][c*9+bin]
        int idx = (bid - 4096) * 256 + t;
        int cb = idx >> 8, c = idx & 255;
        int cls = cb / 9, bin = cb - cls * 9;
        w_bin[idx] = f2bf((cb < 243) ? wfc[cls * FEAT_ + c * 9 + bin] : 0.0f);
        return;
    }
    // w2s[k][c] = w2[c][k] * sc2[c]  (LDS-tiled transpose), 64 blocks
    const int b2id = bid - 4096 - 256;
    const int kt = b2id & 15, ct = b2id >> 4;
    const int rr = t >> 6, cc = t & 63;
    #pragma unroll
    for (int it = 0; it < 16; ++it) {
        int row = it * 4 + rr;
        ld[row][cc] = w2[(size_t)(ct * 64 + row) * CIN_ + kt * 64 + cc];
    }
    __syncthreads();
    float sc = g2[ct * 64 + cc] * rsqrtf(v2[ct * 64 + cc] + 1e-5f);
    #pragma unroll
    for (int it = 0; it < 16; ++it) {
        int krow = it * 4 + rr;
        w2s[(size_t)(kt * 64 + krow) * CMID_ + ct * 64 + cc] = f2bf(ld[cc][krow] * sc);
    }
}

// ---------------- prep: cfc[cls] = bfc[cls] + sum_bin sum_c w_bin[cb][c]*bi2[c] ------
__global__ __launch_bounds__(256) void k_cfc(const u16* __restrict__ w_bin,
                                             const float* __restrict__ g2,
                                             const float* __restrict__ b2,
                                             const float* __restrict__ m2,
                                             const float* __restrict__ v2,
                                             const float* __restrict__ bfc,
                                             float* __restrict__ cfc) {
    __shared__ float ps[4];
    const int cls = blockIdx.x, t = threadIdx.x;
    float bi2 = b2[t] - m2[t] * (g2[t] * rsqrtf(v2[t] + 1e-5f));
    float s = 0.0f;
    #pragma unroll
    for (int bin = 0; bin < 9; ++bin)
        s += bf2f(w_bin[(cls * 9 + bin) * 256 + t]) * bi2;
    #pragma unroll
    for (int o = 32; o > 0; o >>= 1) s += __shfl_xor(s, o, 64);
    if ((t & 63) == 0) ps[t >> 6] = s;
    __syncthreads();
    if (t == 0) cfc[cls] = bfc[cls] + ps[0] + ps[1] + ps[2] + ps[3];
}

// ---------------- K0: NCHW fp32 -> NHWC bf16, LDS-tiled ----------------
__global__ __launch_bounds__(256) void k_nchw_to_nhwc(const float* __restrict__ in,
                                                      u16* __restrict__ out) {
    __shared__ float lds[64][197];
    const int bid = blockIdx.x;
    const int b = bid >> 4, c0 = (bid & 15) << 6;
    const int t = threadIdx.x;
    const float* src = in + ((size_t)b * CIN_ + c0) * HW_;
    #pragma unroll
    for (int it = 0; it < 49; ++it) {
        int idx = it * 256 + t;
        int ci = idx / 196;
        int hw = idx - ci * 196;
        lds[ci][hw] = src[idx];
    }
    __syncthreads();
    u16* dst = out + (size_t)b * HW_ * CIN_ + c0;
    #pragma unroll
    for (int it = 0; it < 49; ++it) {
        int idx = it * 256 + t;
        int hw = idx >> 6, ci = idx & 63;
        dst[(size_t)hw * CIN_ + ci] = f2bf(lds[ci][hw]);
    }
}

// ---------------- K1: conv1 GEMM 64x64 tile, BK=64, reg-prefetch + BN -> bf16 --------
__global__ __launch_bounds__(256) void k_gemm1(
    const u16* __restrict__ A, const u16* __restrict__ Bw,
    const float* __restrict__ gg, const float* __restrict__ bb,
    const float* __restrict__ mm, const float* __restrict__ vv,
    u16* __restrict__ outp)
{
    __shared__ u16 As[64][72];
    __shared__ u16 Bs[64][72];
    const int bid = blockIdx.x;
    const int swz = (bid & 7) * 98 + (bid >> 3);    // bijective: 784 = 8*98
    const int row0 = (swz >> 4) * 64, col0 = (swz & 15) * 64;
    const int t = threadIdx.x, w = t >> 6, lane = t & 63;
    const int wr = (w >> 1) * 32, wc = (w & 1) * 32;
    const int fr = lane & 15, fk = (lane >> 4) * 8;
    const int sr = t >> 2, sk = (t & 3) * 16;
    f32x4 acc[2][2] = {};

    const u16* Ap = A + (size_t)(row0 + sr) * CIN_ + sk;
    const u16* Bp = Bw + (size_t)(col0 + sr) * CIN_ + sk;
    uint4 a0 = *reinterpret_cast<const uint4*>(Ap);
    uint4 a1 = *reinterpret_cast<const uint4*>(Ap + 8);
    uint4 b0 = *reinterpret_cast<const uint4*>(Bp);
    uint4 b1 = *reinterpret_cast<const uint4*>(Bp + 8);
    for (int kt = 0; kt < 16; ++kt) {
        *reinterpret_cast<uint4*>(&As[sr][sk]) = a0;
        *reinterpret_cast<uint4*>(&As[sr][sk + 8]) = a1;
        *reinterpret_cast<uint4*>(&Bs[sr][sk]) = b0;
        *reinterpret_cast<uint4*>(&Bs[sr][sk + 8]) = b1;
        __syncthreads();
        if (kt < 15) {
            const int k0 = (kt + 1) * 64;
            a0 = *reinterpret_cast<const uint4*>(Ap + k0);
            a1 = *reinterpret_cast<const uint4*>(Ap + k0 + 8);
            b0 = *reinterpret_cast<const uint4*>(Bp + k0);
            b1 = *reinterpret_cast<const uint4*>(Bp + k0 + 8);
        }
        #pragma unroll
        for (int kk = 0; kk < 2; ++kk) {
            const int ko = fk + kk * 32;
            bf16x8 af0 = *reinterpret_cast<bf16x8*>(&As[wr + fr][ko]);
            bf16x8 af1 = *reinterpret_cast<bf16x8*>(&As[wr + 16 + fr][ko]);
            bf16x8 bf0 = *reinterpret_cast<bf16x8*>(&Bs[wc + fr][ko]);
            bf16x8 bf1 = *reinterpret_cast<bf16x8*>(&Bs[wc + 16 + fr][ko]);
            acc[0][0] = __builtin_amdgcn_mfma_f32_16x16x32_bf16(af0, bf0, acc[0][0], 0, 0, 0);
            acc[0][1] = __builtin_amdgcn_mfma_f32_16x16x32_bf16(af0, bf1, acc[0][1], 0, 0, 0);
            acc[1][0] = __builtin_amdgcn_mfma_f32_16x16x32_bf16(af1, bf0, acc[1][0], 0, 0, 0);
            acc[1][1] = __builtin_amdgcn_mfma_f32_16x16x32_bf16(af1, bf1, acc[1][1], 0, 0, 0);
        }
        __syncthreads();
    }
    #pragma unroll
    for (int ni = 0; ni < 2; ++ni) {
        int col = col0 + wc + ni * 16 + fr;
        float sc = gg[col] * rsqrtf(vv[col] + 1e-5f);
        float bi = bb[col] - mm[col] * sc;
        #pragma unroll
        for (int mi = 0; mi < 2; ++mi) {
            #pragma unroll
            for (int rgi = 0; rgi < 4; ++rgi) {
                int row = row0 + wr + mi * 16 + (lane >> 4) * 4 + rgi;
                outp[(size_t)row * CIN_ + col] = f2bf(acc[mi][ni][rgi] * sc + bi);
            }
        }
    }
}

// ---------------- K2: generic GEMM (64x64 tile, 256 thr), bf16 out, no BN -----------
__global__ __launch_bounds__(256) void k_gemm_plain(
    const u16* __restrict__ A, const u16* __restrict__ Bw,
    u16* __restrict__ outp, int N, int K)
{
    __shared__ u16 As[64][40];
    __shared__ u16 Bs[64][40];
    const int row0 = blockIdx.y * 64, col0 = blockIdx.x * 64;
    const int t = threadIdx.x;
    const int lr = t >> 2, lk = (t & 3) * 8;
    const int wave = t >> 6, lane = t & 63;
    const int wr = (wave >> 1) * 32, wc = (wave & 1) * 32;
    const int fr = lane & 15, fk = (lane >> 4) * 8;
    f32x4 acc[2][2] = {};
    const u16* Aptr = A + (size_t)(row0 + lr) * K + lk;
    const u16* Bptr = Bw + (size_t)(col0 + lr) * K + lk;
    for (int k0 = 0; k0 < K; k0 += 32) {
        *reinterpret_cast<uint4*>(&As[lr][lk]) = *reinterpret_cast<const uint4*>(Aptr + k0);
        *reinterpret_cast<uint4*>(&Bs[lr][lk]) = *reinterpret_cast<const uint4*>(Bptr + k0);
        __syncthreads();
        bf16x8 a0 = *reinterpret_cast<bf16x8*>(&As[wr + fr][fk]);
        bf16x8 a1 = *reinterpret_cast<bf16x8*>(&As[wr + 16 + fr][fk]);
        bf16x8 b0 = *reinterpret_cast<bf16x8*>(&Bs[wc + fr][fk]);
        bf16x8 b1 = *reinterpret_cast<bf16x8*>(&Bs[wc + 16 + fr][fk]);
        acc[0][0] = __builtin_amdgcn_mfma_f32_16x16x32_bf16(a0, b0, acc[0][0], 0, 0, 0);
        acc[0][1] = __builtin_amdgcn_mfma_f32_16x16x32_bf16(a0, b1, acc[0][1], 0, 0, 0);
        acc[1][0] = __builtin_amdgcn_mfma_f32_16x16x32_bf16(a1, b0, acc[1][0], 0, 0, 0);
        acc[1][1] = __builtin_amdgcn_mfma_f32_16x16x32_bf16(a1, b1, acc[1][1], 0, 0, 0);
        __syncthreads();
    }
    #pragma unroll
    for (int ni = 0; ni < 2; ++ni) {
        int col = col0 + wc + ni * 16 + fr;
        #pragma unroll
        for (int mi = 0; mi < 2; ++mi) {
            #pragma unroll
            for (int rgi = 0; rgi < 4; ++rgi) {
                int row = row0 + wr + mi * 16 + (lane >> 4) * 4 + rgi;
                outp[(size_t)row * N + col] = f2bf(acc[mi][ni][rgi]);
            }
        }
    }
}

// ---------------- K2b: G-GEMM with in-block split-K (512 thr = 2 x 4-wave halves) ----
// G16[m][cb] = sum_k h[m][k] * wG[cb][k], K=1024 split 2x512. Fixes the 196-block
// occupancy trap (1 wave/SIMD -> 2).
__global__ __launch_bounds__(512) void k_gemmG(
    const u16* __restrict__ A, const u16* __restrict__ Bw, u16* __restrict__ outp)
{
    __shared__ u16 As[2][64][40];
    __shared__ u16 Bs[2][64][40];
    __shared__ float red[4096];
    const int row0 = blockIdx.y * 64, col0 = blockIdx.x * 64;
    const int t = threadIdx.x, kw = t >> 8, tt = t & 255;
    const int wave = tt >> 6, lane = tt & 63;
    const int wr = (wave >> 1) * 32, wc = (wave & 1) * 32;
    const int fr = lane & 15, fk = (lane >> 4) * 8;
    const int lr = tt >> 2, lk = (tt & 3) * 8;
    f32x4 acc[2][2] = {};
    const u16* Aptr = A + (size_t)(row0 + lr) * CIN_ + kw * 512 + lk;
    const u16* Bptr = Bw + (size_t)(col0 + lr) * CIN_ + kw * 512 + lk;
    for (int k0 = 0; k0 < 512; k0 += 32) {
        *reinterpret_cast<uint4*>(&As[kw][lr][lk]) = *reinterpret_cast<const uint4*>(Aptr + k0);
        *reinterpret_cast<uint4*>(&Bs[kw][lr][lk]) = *reinterpret_cast<const uint4*>(Bptr + k0);
        __syncthreads();
        bf16x8 a0 = *reinterpret_cast<bf16x8*>(&As[kw][wr + fr][fk]);
        bf16x8 a1 = *reinterpret_cast<bf16x8*>(&As[kw][wr + 16 + fr][fk]);
        bf16x8 b0 = *reinterpret_cast<bf16x8*>(&Bs[kw][wc + fr][fk]);
        bf16x8 b1 = *reinterpret_cast<bf16x8*>(&Bs[kw][wc + 16 + fr][fk]);
        acc[0][0] = __builtin_amdgcn_mfma_f32_16x16x32_bf16(a0, b0, acc[0][0], 0, 0, 0);
        acc[0][1] = __builtin_amdgcn_mfma_f32_16x16x32_bf16(a0, b1, acc[0][1], 0, 0, 0);
        acc[1][0] = __builtin_amdgcn_mfma_f32_16x16x32_bf16(a1, b0, acc[1][0], 0, 0, 0);
        acc[1][1] = __builtin_amdgcn_mfma_f32_16x16x32_bf16(a1, b1, acc[1][1], 0, 0, 0);
        __syncthreads();
    }
    if (kw == 1) {
        #pragma unroll
        for (int mi = 0; mi < 2; ++mi)
            #pragma unroll
            for (int ni = 0; ni < 2; ++ni)
                #pragma unroll
                for (int rgi = 0; rgi < 4; ++rgi)
                    red[wave * 1024 + lane * 16 + (mi * 2 + ni) * 4 + rgi] = acc[mi][ni][rgi];
    }
    __syncthreads();
    if (kw == 0) {
        #pragma unroll
        for (int mi = 0; mi < 2; ++mi) {
            #pragma unroll
            for (int ni = 0; ni < 2; ++ni) {
                int col = col0 + wc + ni * 16 + fr;
                #pragma unroll
                for (int rgi = 0; rgi < 4; ++rgi) {
                    int row = row0 + wr + mi * 16 + (lane >> 4) * 4 + rgi;
                    float s = acc[mi][ni][rgi]
                            + red[wave * 1024 + lane * 16 + (mi * 2 + ni) * 4 + rgi];
                    outp[(size_t)row * NCB_ + col] = f2bf(s);
                }
            }
        }
    }
}

// ---------------- K3: roi pooling on bf16 G -> logits ----------------
__global__ __launch_bounds__(256) void k_roi_logits(
    const float* __restrict__ boxes, const u16* __restrict__ G,
    const float* __restrict__ cfc, float* __restrict__ out)
{
    __shared__ float sred[4][260];
    const int t = threadIdx.x, w = t >> 6, lane = t & 63;
    const int r = blockIdx.x * 4 + w;
    const int b = r / ROIS_;
    const float* bxp = boxes + (size_t)r * 4;
    float x1 = bxp[0], y1 = bxp[1];
    float rw = fmaxf(bxp[2] - x1, 1.0f), rh = fmaxf(bxp[3] - y1, 1.0f);
    float sx = rw * (1.0f / 3.0f), sy = rh * (1.0f / 3.0f);
    const float OFFS[6] = {0.25f, 0.75f, 1.25f, 1.75f, 2.25f, 2.75f};

    int xl[6], xh[6], yl[6], yh[6];
    float lx[6], hx[6], ly[6], hy[6];
    #pragma unroll
    for (int i = 0; i < 6; ++i) {
        float xx = fmaxf(x1 + OFFS[i] * sx, 0.0f);
        xl[i] = min((int)xx, 13); xh[i] = min(xl[i] + 1, 13);
        float xv = (xl[i] == 13) ? 13.0f : xx;
        lx[i] = xv - (float)xl[i]; hx[i] = 1.0f - lx[i];
        float yy = fmaxf(y1 + OFFS[i] * sy, 0.0f);
        yl[i] = min((int)yy, 13); yh[i] = min(yl[i] + 1, 13);
        float yv = (yl[i] == 13) ? 13.0f : yy;
        ly[i] = yv - (float)yl[i]; hy[i] = 1.0f - ly[i];
    }
    const int xc0 = min(xl[0], 8), yr0 = min(yl[0], 8);

    float WX[3][6], WY[3][6];
    #pragma unroll
    for (int bi = 0; bi < 3; ++bi)
        #pragma unroll
        for (int c = 0; c < 6; ++c) { WX[bi][c] = 0.0f; WY[bi][c] = 0.0f; }
    #pragma unroll
    for (int i = 0; i < 6; ++i) {
        const int bi = i >> 1;
        #pragma unroll
        for (int c = 0; c < 6; ++c) {
            WX[bi][c] += (xl[i] - xc0 == c ? hx[i] : 0.0f)
                       + (xh[i] - xc0 == c ? lx[i] : 0.0f);
            WY[bi][c] += (yl[i] - yr0 == c ? hy[i] : 0.0f)
                       + (yh[i] - yr0 == c ? ly[i] : 0.0f);
        }
    }

    int bxj[4], byj[4];
    #pragma unroll
    for (int j = 0; j < 4; ++j) {
        int cb = lane * 4 + j;
        int cls = cb / 9;
        int bin = cb - cls * 9;
        bxj[j] = bin % 3; byj[j] = bin / 3;
    }
    f32x4 wx4[6], wy4[6];
    #pragma unroll
    for (int q = 0; q < 6; ++q) {
        #pragma unroll
        for (int j = 0; j < 4; ++j) {
            wx4[q][j] = (bxj[j] == 0) ? WX[0][q] : ((bxj[j] == 1) ? WX[1][q] : WX[2][q]);
            wy4[q][j] = (byj[j] == 0) ? WY[0][q] : ((byj[j] == 1) ? WY[1][q] : WY[2][q]);
        }
    }

    const u16* base = G + ((size_t)b * HW_ + yr0 * 14 + xc0) * NCB_ + lane * 4;
    f32x4 acc = {};
    #pragma unroll
    for (int rr = 0; rr < 6; ++rr) {
        const u16* rp = base + rr * (14 * NCB_);
        f32x4 tmp = {};
        #pragma unroll
        for (int cc = 0; cc < 6; ++cc) {
            uint2 gu = *reinterpret_cast<const uint2*>(rp + cc * NCB_);
            f32x4 g;
            g[0] = bits2f(gu.x << 16); g[1] = bits2f(gu.x & 0xFFFF0000u);
            g[2] = bits2f(gu.y << 16); g[3] = bits2f(gu.y & 0xFFFF0000u);
            tmp += g * wx4[cc];
        }
        acc += tmp * wy4[rr];
    }
    acc *= 0.25f;
    #pragma unroll
    for (int j = 0; j < 4; ++j) sred[w][lane * 4 + j] = acc[j];
    __syncthreads();
    if (lane < NCLS_) {
        float s = cfc[lane];
        #pragma unroll
        for (int bin = 0; bin < 9; ++bin) s += sred[w][lane * 9 + bin];
        out[(size_t)r * NCLS_ + lane] = s;
    }
}

extern "C" void kernel_launch(void* const* d_in, const int* in_sizes, int n_in,
                              void* d_out, int out_size, void* d_ws, size_t ws_size,
                              hipStream_t stream) {
    const float* boxes   = (const float*)d_in[0];
    const float* fmap_in = (const float*)d_in[1];
    const float* w1 = (const float*)d_in[2];
    const float* g1 = (const float*)d_in[3];
    const float* b1 = (const float*)d_in[4];
    const float* m1 = (const float*)d_in[5];
    const float* v1 = (const float*)d_in[6];
    const float* w2 = (const float*)d_in[7];
    const float* g2 = (const float*)d_in[8];
    const float* b2 = (const float*)d_in[9];
    const float* m2 = (const float*)d_in[10];
    const float* v2 = (const float*)d_in[11];
    const float* wfc = (const float*)d_in[12];
    const float* bfc = (const float*)d_in[13];

    char* ws = (char*)d_ws;
    u16*   Anhwc = (u16*)(ws + 0);                   // 6,422,528 B
    u16*   G16   = (u16*)(ws + 0);                   // 1,605,632 B (aliases Anhwc; dead after gemm1)
    u16*   h     = (u16*)(ws + 6422528);             // 6,422,528 B
    u16*   w1b   = (u16*)(ws + 14450688);            // 2,097,152 B
    u16*   w_bin = (u16*)(ws + 16547840);            //   131,072 B
    u16*   w2s   = (u16*)(ws + 16678912);            //   524,288 B
    u16*   wG    = (u16*)(ws + 17203200);            //   524,288 B
    float* cfc   = (float*)(ws + 17727488);          //       128 B

    hipLaunchKernelGGL(k_prep, dim3(4096 + 256 + 64), dim3(256), 0, stream,
                       w1, w1b, wfc, w_bin, w2, g2, v2, w2s);
    // wG[cb][k] = sum_c w_bin[cb][c] * w2s[k][c]   (M=256, N=1024, K=256) -> bf16
    hipLaunchKernelGGL(k_gemm_plain, dim3(CIN_ / 64, NCB_ / 64), dim3(256), 0, stream,
                       w_bin, w2s, wG, CIN_, CMID_);
    hipLaunchKernelGGL(k_cfc, dim3(NCLS_), dim3(256), 0, stream,
                       w_bin, g2, b2, m2, v2, bfc, cfc);
    hipLaunchKernelGGL(k_nchw_to_nhwc, dim3(NB_ * 16), dim3(256), 0, stream,
                       fmap_in, Anhwc);
    hipLaunchKernelGGL(k_gemm1, dim3(784), dim3(256), 0, stream,
                       Anhwc, w1b, g1, b1, m1, v1, h);
    // G16 = h * wG^T  (M=3136, N=256, K=1024 split 2x512) -> bf16
    hipLaunchKernelGGL(k_gemmG, dim3(NCB_ / 64, M_ / 64), dim3(512), 0, stream,
                       h, wG, G16);
    hipLaunchKernelGGL(k_roi_logits, dim3(NROI_ / 4), dim3(256), 0, stream,
                       boxes, G16, cfc, (float*)d_out);
}

// Round 13
// 72.817 us; speedup vs baseline: 1.6560x; 1.1698x over previous
//
#include <hip/hip_runtime.h>
#include <hip/hip_bf16.h>
#include <math.h>

#define H_ 14
#define W_ 14
#define HW_ 196
#define CIN_ 1024
#define CMID_ 256
#define NCLS_ 27
#define NB_ 16
#define ROIS_ 980
#define M_ 3136
#define FEAT_ 2304
#define NROI_ (NB_ * ROIS_)   // 15680
#define NCB_ 256              // padded cb = cls*9+bin (243 real)

typedef unsigned short u16;
typedef __attribute__((ext_vector_type(8))) short bf16x8;
typedef __attribute__((ext_vector_type(4))) float f32x4;

__device__ __forceinline__ float bf2f(u16 u) {
    union { unsigned int i; float f; } x; x.i = ((unsigned int)u) << 16; return x.f;
}
__device__ __forceinline__ float bits2f(unsigned int u) {
    union { unsigned int i; float f; } x; x.i = u; return x.f;
}
__device__ __forceinline__ u16 f2bf(float f) {
    __hip_bfloat16 h = __float2bfloat16(f);
    return *reinterpret_cast<u16*>(&h);
}

// ---------------- merged prep ----------------
// blocks [0,256):   w_bin[cb][c] = wfc[cls][c*9+bin]                (bf16, pad cb>=243)
// blocks [256,320): w2s[o][cmid] = w2[cmid][o]*sc2[cmid]            (LDS transpose)
// blocks [320,576): w1ts[c][o]   = w1[o][c]*sc1[o]                  (LDS transpose)
// blocks [576,832): Anhwc[b][hw][c] = bf16(fmap_in[b][c][hw])       (LDS transpose)
__global__ __launch_bounds__(256) void k_prep(
    const float* __restrict__ wfc, u16* __restrict__ w_bin,
    const float* __restrict__ w2, const float* __restrict__ g2,
    const float* __restrict__ v2, u16* __restrict__ w2s,
    const float* __restrict__ w1, const float* __restrict__ g1,
    const float* __restrict__ v1, u16* __restrict__ w1ts,
    const float* __restrict__ fmap_in, u16* __restrict__ anhwc)
{
    __shared__ float ld[64][197];
    float (*ld65)[65] = (float(*)[65])&ld[0][0];
    const int bid = blockIdx.x, t = threadIdx.x;
    if (bid < 256) {                       // w_bin
        int idx = bid * 256 + t;
        int cb = idx >> 8, c = idx & 255;
        int cls = cb / 9, bin = cb - cls * 9;
        w_bin[idx] = f2bf((cb < 243) ? wfc[cls * FEAT_ + c * 9 + bin] : 0.0f);
        return;
    }
    if (bid < 320) {                       // w2s: in w2[256][1024] -> out [1024][256]
        const int b2id = bid - 256;
        const int kt = b2id & 15, ct = b2id >> 4;   // kt: o-tile, ct: cmid-tile
        const int rr = t >> 6, cc = t & 63;
        #pragma unroll
        for (int it = 0; it < 16; ++it) {
            int row = it * 4 + rr;
            ld65[row][cc] = w2[(size_t)(ct * 64 + row) * CIN_ + kt * 64 + cc];
        }
        __syncthreads();
        float sc = g2[ct * 64 + cc] * rsqrtf(v2[ct * 64 + cc] + 1e-5f);
        #pragma unroll
        for (int it = 0; it < 16; ++it) {
            int krow = it * 4 + rr;
            w2s[(size_t)(kt * 64 + krow) * CMID_ + ct * 64 + cc] = f2bf(ld65[cc][krow] * sc);
        }
        return;
    }
    if (bid < 576) {                       // w1ts: in w1[1024 o][1024 c] -> out [c][o]*sc1[o]
        const int b1id = bid - 320;
        const int ot = b1id & 15, ct = b1id >> 4;
        const int rr = t >> 6, cc = t & 63;
        #pragma unroll
        for (int it = 0; it < 16; ++it) {
            int row = it * 4 + rr;         // o_local
            ld65[row][cc] = w1[(size_t)(ot * 64 + row) * CIN_ + ct * 64 + cc];
        }
        __syncthreads();
        float sc = g1[ot * 64 + cc] * rsqrtf(v1[ot * 64 + cc] + 1e-5f);
        #pragma unroll
        for (int it = 0; it < 16; ++it) {
            int crow = it * 4 + rr;        // c_local
            w1ts[(size_t)(ct * 64 + crow) * CIN_ + ot * 64 + cc] = f2bf(ld65[cc][crow] * sc);
        }
        return;
    }
    // NCHW -> NHWC bf16
    const int bn = bid - 576;
    const int b = bn >> 4, c0 = (bn & 15) << 6;
    const float* src = fmap_in + ((size_t)b * CIN_ + c0) * HW_;
    #pragma unroll
    for (int it = 0; it < 49; ++it) {
        int idx = it * 256 + t;
        int ci = idx / 196;
        int hw = idx - ci * 196;
        ld[ci][hw] = src[idx];
    }
    __syncthreads();
    u16* dst = anhwc + (size_t)b * HW_ * CIN_ + c0;
    #pragma unroll
    for (int it = 0; it < 49; ++it) {
        int idx = it * 256 + t;
        int hw = idx >> 6, ci = idx & 63;
        dst[(size_t)hw * CIN_ + ci] = f2bf(ld[ci][hw]);
    }
}

// ---------------- prep: cfc[cls] = bfc + sum_bin (w_bin.bi2 + wG.bi1) ----------------
__global__ __launch_bounds__(256) void k_cfc(
    const u16* __restrict__ w_bin, const u16* __restrict__ wG,
    const float* __restrict__ g1, const float* __restrict__ b1,
    const float* __restrict__ m1, const float* __restrict__ v1,
    const float* __restrict__ g2, const float* __restrict__ b2,
    const float* __restrict__ m2, const float* __restrict__ v2,
    const float* __restrict__ bfc, float* __restrict__ cfc)
{
    __shared__ float ps[4];
    const int cls = blockIdx.x, t = threadIdx.x;
    float bi2 = b2[t] - m2[t] * (g2[t] * rsqrtf(v2[t] + 1e-5f));
    float s = 0.0f;
    #pragma unroll
    for (int bin = 0; bin < 9; ++bin)
        s += bf2f(w_bin[(cls * 9 + bin) * 256 + t]) * bi2;
    #pragma unroll
    for (int j = 0; j < 4; ++j) {
        int o = t + 256 * j;
        float bi1 = b1[o] - m1[o] * (g1[o] * rsqrtf(v1[o] + 1e-5f));
        #pragma unroll
        for (int bin = 0; bin < 9; ++bin)
            s += bf2f(wG[(size_t)(cls * 9 + bin) * CIN_ + o]) * bi1;
    }
    #pragma unroll
    for (int o = 32; o > 0; o >>= 1) s += __shfl_xor(s, o, 64);
    if ((t & 63) == 0) ps[t >> 6] = s;
    __syncthreads();
    if (t == 0) cfc[cls] = bfc[cls] + ps[0] + ps[1] + ps[2] + ps[3];
}

// ---------------- generic split-K GEMM: out[m][n] = sum_k A[m][k]*B[n][k], bf16 out --
// 512 thr = 2 x (4-wave 64x64 sub-GEMM over K/2). Keeps 2 waves/SIMD even on tiny
// grids (the 64..196-block occupancy trap).
__global__ __launch_bounds__(512) void k_gemm_sk(
    const u16* __restrict__ A, const u16* __restrict__ Bw, u16* __restrict__ outp,
    int N, int K)
{
    __shared__ u16 As[2][64][40];
    __shared__ u16 Bs[2][64][40];
    __shared__ float red[4096];
    const int row0 = blockIdx.y * 64, col0 = blockIdx.x * 64;
    const int t = threadIdx.x, kw = t >> 8, tt = t & 255;
    const int wave = tt >> 6, lane = tt & 63;
    const int wr = (wave >> 1) * 32, wc = (wave & 1) * 32;
    const int fr = lane & 15, fk = (lane >> 4) * 8;
    const int lr = tt >> 2, lk = (tt & 3) * 8;
    const int Kh = K >> 1;
    f32x4 acc[2][2] = {};
    const u16* Aptr = A + (size_t)(row0 + lr) * K + kw * Kh + lk;
    const u16* Bptr = Bw + (size_t)(col0 + lr) * K + kw * Kh + lk;
    for (int k0 = 0; k0 < Kh; k0 += 32) {
        *reinterpret_cast<uint4*>(&As[kw][lr][lk]) = *reinterpret_cast<const uint4*>(Aptr + k0);
        *reinterpret_cast<uint4*>(&Bs[kw][lr][lk]) = *reinterpret_cast<const uint4*>(Bptr + k0);
        __syncthreads();
        bf16x8 a0 = *reinterpret_cast<bf16x8*>(&As[kw][wr + fr][fk]);
        bf16x8 a1 = *reinterpret_cast<bf16x8*>(&As[kw][wr + 16 + fr][fk]);
        bf16x8 b0 = *reinterpret_cast<bf16x8*>(&Bs[kw][wc + fr][fk]);
        bf16x8 b1 = *reinterpret_cast<bf16x8*>(&Bs[kw][wc + 16 + fr][fk]);
        acc[0][0] = __builtin_amdgcn_mfma_f32_16x16x32_bf16(a0, b0, acc[0][0], 0, 0, 0);
        acc[0][1] = __builtin_amdgcn_mfma_f32_16x16x32_bf16(a0, b1, acc[0][1], 0, 0, 0);
        acc[1][0] = __builtin_amdgcn_mfma_f32_16x16x32_bf16(a1, b0, acc[1][0], 0, 0, 0);
        acc[1][1] = __builtin_amdgcn_mfma_f32_16x16x32_bf16(a1, b1, acc[1][1], 0, 0, 0);
        __syncthreads();
    }
    if (kw == 1) {
        #pragma unroll
        for (int mi = 0; mi < 2; ++mi)
            #pragma unroll
            for (int ni = 0; ni < 2; ++ni)
                #pragma unroll
                for (int rgi = 0; rgi < 4; ++rgi)
                    red[wave * 1024 + lane * 16 + (mi * 2 + ni) * 4 + rgi] = acc[mi][ni][rgi];
    }
    __syncthreads();
    if (kw == 0) {
        #pragma unroll
        for (int mi = 0; mi < 2; ++mi) {
            #pragma unroll
            for (int ni = 0; ni < 2; ++ni) {
                int col = col0 + wc + ni * 16 + fr;
                #pragma unroll
                for (int rgi = 0; rgi < 4; ++rgi) {
                    int row = row0 + wr + mi * 16 + (lane >> 4) * 4 + rgi;
                    float s = acc[mi][ni][rgi]
                            + red[wave * 1024 + lane * 16 + (mi * 2 + ni) * 4 + rgi];
                    outp[(size_t)row * N + col] = f2bf(s);
                }
            }
        }
    }
}

// ---------------- K3: roi pooling on bf16 G -> logits ----------------
__global__ __launch_bounds__(256) void k_roi_logits(
    const float* __restrict__ boxes, const u16* __restrict__ G,
    const float* __restrict__ cfc, float* __restrict__ out)
{
    __shared__ float sred[4][260];
    const int t = threadIdx.x, w = t >> 6, lane = t & 63;
    const int r = blockIdx.x * 4 + w;
    const int b = r / ROIS_;
    const float* bxp = boxes + (size_t)r * 4;
    float x1 = bxp[0], y1 = bxp[1];
    float rw = fmaxf(bxp[2] - x1, 1.0f), rh = fmaxf(bxp[3] - y1, 1.0f);
    float sx = rw * (1.0f / 3.0f), sy = rh * (1.0f / 3.0f);
    const float OFFS[6] = {0.25f, 0.75f, 1.25f, 1.75f, 2.25f, 2.75f};

    int xl[6], xh[6], yl[6], yh[6];
    float lx[6], hx[6], ly[6], hy[6];
    #pragma unroll
    for (int i = 0; i < 6; ++i) {
        float xx = fmaxf(x1 + OFFS[i] * sx, 0.0f);
        xl[i] = min((int)xx, 13); xh[i] = min(xl[i] + 1, 13);
        float xv = (xl[i] == 13) ? 13.0f : xx;
        lx[i] = xv - (float)xl[i]; hx[i] = 1.0f - lx[i];
        float yy = fmaxf(y1 + OFFS[i] * sy, 0.0f);
        yl[i] = min((int)yy, 13); yh[i] = min(yl[i] + 1, 13);
        float yv = (yl[i] == 13) ? 13.0f : yy;
        ly[i] = yv - (float)yl[i]; hy[i] = 1.0f - ly[i];
    }
    const int xc0 = min(xl[0], 8), yr0 = min(yl[0], 8);

    float WX[3][6], WY[3][6];
    #pragma unroll
    for (int bi = 0; bi < 3; ++bi)
        #pragma unroll
        for (int c = 0; c < 6; ++c) { WX[bi][c] = 0.0f; WY[bi][c] = 0.0f; }
    #pragma unroll
    for (int i = 0; i < 6; ++i) {
        const int bi = i >> 1;
        #pragma unroll
        for (int c = 0; c < 6; ++c) {
            WX[bi][c] += (xl[i] - xc0 == c ? hx[i] : 0.0f)
                       + (xh[i] - xc0 == c ? lx[i] : 0.0f);
            WY[bi][c] += (yl[i] - yr0 == c ? hy[i] : 0.0f)
                       + (yh[i] - yr0 == c ? ly[i] : 0.0f);
        }
    }

    int bxj[4], byj[4];
    #pragma unroll
    for (int j = 0; j < 4; ++j) {
        int cb = lane * 4 + j;
        int cls = cb / 9;
        int bin = cb - cls * 9;
        bxj[j] = bin % 3; byj[j] = bin / 3;
    }
    f32x4 wx4[6], wy4[6];
    #pragma unroll
    for (int q = 0; q < 6; ++q) {
        #pragma unroll
        for (int j = 0; j < 4; ++j) {
            wx4[q][j] = (bxj[j] == 0) ? WX[0][q] : ((bxj[j] == 1) ? WX[1][q] : WX[2][q]);
            wy4[q][j] = (byj[j] == 0) ? WY[0][q] : ((byj[j] == 1) ? WY[1][q] : WY[2][q]);
        }
    }

    const u16* base = G + ((size_t)b * HW_ + yr0 * 14 + xc0) * NCB_ + lane * 4;
    f32x4 acc = {};
    #pragma unroll
    for (int rr = 0; rr < 6; ++rr) {
        const u16* rp = base + rr * (14 * NCB_);
        f32x4 tmp = {};
        #pragma unroll
        for (int cc = 0; cc < 6; ++cc) {
            uint2 gu = *reinterpret_cast<const uint2*>(rp + cc * NCB_);
            f32x4 g;
            g[0] = bits2f(gu.x << 16); g[1] = bits2f(gu.x & 0xFFFF0000u);
            g[2] = bits2f(gu.y << 16); g[3] = bits2f(gu.y & 0xFFFF0000u);
            tmp += g * wx4[cc];
        }
        acc += tmp * wy4[rr];
    }
    acc *= 0.25f;
    #pragma unroll
    for (int j = 0; j < 4; ++j) sred[w][lane * 4 + j] = acc[j];
    __syncthreads();
    if (lane < NCLS_) {
        float s = cfc[lane];
        #pragma unroll
        for (int bin = 0; bin < 9; ++bin) s += sred[w][lane * 9 + bin];
        out[(size_t)r * NCLS_ + lane] = s;
    }
}

extern "C" void kernel_launch(void* const* d_in, const int* in_sizes, int n_in,
                              void* d_out, int out_size, void* d_ws, size_t ws_size,
                              hipStream_t stream) {
    const float* boxes   = (const float*)d_in[0];
    const float* fmap_in = (const float*)d_in[1];
    const float* w1 = (const float*)d_in[2];
    const float* g1 = (const float*)d_in[3];
    const float* b1 = (const float*)d_in[4];
    const float* m1 = (const float*)d_in[5];
    const float* v1 = (const float*)d_in[6];
    const float* w2 = (const float*)d_in[7];
    const float* g2 = (const float*)d_in[8];
    const float* b2 = (const float*)d_in[9];
    const float* m2 = (const float*)d_in[10];
    const float* v2 = (const float*)d_in[11];
    const float* wfc = (const float*)d_in[12];
    const float* bfc = (const float*)d_in[13];

    char* ws = (char*)d_ws;
    u16*   Anhwc = (u16*)(ws + 0);                   //  6,422,528 B
    u16*   G16   = (u16*)(ws + 6422528);             //  1,605,632 B
    u16*   w_bin = (u16*)(ws + 8028160);             //    131,072 B
    u16*   w2s   = (u16*)(ws + 8159232);             //    524,288 B
    u16*   w1ts  = (u16*)(ws + 8683520);             //  2,097,152 B
    u16*   wG    = (u16*)(ws + 10780672);            //    524,288 B
    u16*   Wtot  = (u16*)(ws + 11304960);            //    524,288 B
    float* cfc   = (float*)(ws + 11829248);          //        128 B

    hipLaunchKernelGGL(k_prep, dim3(832), dim3(256), 0, stream,
                       wfc, w_bin, w2, g2, v2, w2s, w1, g1, v1, w1ts, fmap_in, Anhwc);
    // wG[cb][o] = sum_cmid w_bin[cb][cmid] * w2s[o][cmid]   (M=256, N=1024, K=256)
    hipLaunchKernelGGL(k_gemm_sk, dim3(CIN_ / 64, NCB_ / 64), dim3(512), 0, stream,
                       w_bin, w2s, wG, CIN_, CMID_);
    // Wtot[cb][c] = sum_o wG[cb][o] * w1ts[c][o]            (M=256, N=1024, K=1024)
    hipLaunchKernelGGL(k_gemm_sk, dim3(CIN_ / 64, NCB_ / 64), dim3(512), 0, stream,
                       wG, w1ts, Wtot, CIN_, CIN_);
    hipLaunchKernelGGL(k_cfc, dim3(NCLS_), dim3(256), 0, stream,
                       w_bin, wG, g1, b1, m1, v1, g2, b2, m2, v2, bfc, cfc);
    // G16[m][cb] = sum_c Anhwc[m][c] * Wtot[cb][c]          (M=3136, N=256, K=1024)
    hipLaunchKernelGGL(k_gemm_sk, dim3(NCB_ / 64, M_ / 64), dim3(512), 0, stream,
                       Anhwc, Wtot, G16, NCB_, CIN_);
    hipLaunchKernelGGL(k_roi_logits, dim3(NROI_ / 4), dim3(256), 0, stream,
                       boxes, G16, cfc, (float*)d_out);
}

// Round 14
// 66.221 us; speedup vs baseline: 1.8210x; 1.0996x over previous
//
#include <hip/hip_runtime.h>
#include <hip/hip_bf16.h>
#include <math.h>

#define H_ 14
#define W_ 14
#define HW_ 196
#define CIN_ 1024
#define CMID_ 256
#define NCLS_ 27
#define NB_ 16
#define ROIS_ 980
#define M_ 3136
#define FEAT_ 2304
#define NROI_ (NB_ * ROIS_)   // 15680
#define NCB_ 256              // padded cb = cls*9+bin (243 real)

typedef unsigned short u16;
typedef __attribute__((ext_vector_type(8))) short bf16x8;
typedef __attribute__((ext_vector_type(4))) float f32x4;

__device__ __forceinline__ float bf2f(u16 u) {
    union { unsigned int i; float f; } x; x.i = ((unsigned int)u) << 16; return x.f;
}
__device__ __forceinline__ float bits2f(unsigned int u) {
    union { unsigned int i; float f; } x; x.i = u; return x.f;
}
__device__ __forceinline__ u16 f2bf(float f) {
    __hip_bfloat16 h = __float2bfloat16(f);
    return *reinterpret_cast<u16*>(&h);
}

// ---------------- merged prep ----------------
// blocks [0,256):   w_bin[cb][c] = wfc[cls][c*9+bin]                (bf16, pad cb>=243)
// blocks [256,320): w2s[o][cmid] = w2[cmid][o]*sc2[cmid]            (LDS transpose)
// blocks [320,576): w1ts[c][o]   = w1[o][c]*sc1[o]                  (LDS transpose)
// blocks [576,832): Anhwc[b][hw][c] = bf16(fmap_in[b][c][hw])       (LDS transpose)
__global__ __launch_bounds__(256) void k_prep(
    const float* __restrict__ wfc, u16* __restrict__ w_bin,
    const float* __restrict__ w2, const float* __restrict__ g2,
    const float* __restrict__ v2, u16* __restrict__ w2s,
    const float* __restrict__ w1, const float* __restrict__ g1,
    const float* __restrict__ v1, u16* __restrict__ w1ts,
    const float* __restrict__ fmap_in, u16* __restrict__ anhwc)
{
    __shared__ float ld[64][197];
    float (*ld65)[65] = (float(*)[65])&ld[0][0];
    const int bid = blockIdx.x, t = threadIdx.x;
    if (bid < 256) {                       // w_bin
        int idx = bid * 256 + t;
        int cb = idx >> 8, c = idx & 255;
        int cls = cb / 9, bin = cb - cls * 9;
        w_bin[idx] = f2bf((cb < 243) ? wfc[cls * FEAT_ + c * 9 + bin] : 0.0f);
        return;
    }
    if (bid < 320) {                       // w2s: in w2[256][1024] -> out [1024][256]
        const int b2id = bid - 256;
        const int kt = b2id & 15, ct = b2id >> 4;
        const int rr = t >> 6, cc = t & 63;
        #pragma unroll
        for (int it = 0; it < 16; ++it) {
            int row = it * 4 + rr;
            ld65[row][cc] = w2[(size_t)(ct * 64 + row) * CIN_ + kt * 64 + cc];
        }
        __syncthreads();
        float sc = g2[ct * 64 + cc] * rsqrtf(v2[ct * 64 + cc] + 1e-5f);
        #pragma unroll
        for (int it = 0; it < 16; ++it) {
            int krow = it * 4 + rr;
            w2s[(size_t)(kt * 64 + krow) * CMID_ + ct * 64 + cc] = f2bf(ld65[cc][krow] * sc);
        }
        return;
    }
    if (bid < 576) {                       // w1ts: in w1[1024 o][1024 c] -> out [c][o]*sc1[o]
        const int b1id = bid - 320;
        const int ot = b1id & 15, ct = b1id >> 4;
        const int rr = t >> 6, cc = t & 63;
        #pragma unroll
        for (int it = 0; it < 16; ++it) {
            int row = it * 4 + rr;         // o_local
            ld65[row][cc] = w1[(size_t)(ot * 64 + row) * CIN_ + ct * 64 + cc];
        }
        __syncthreads();
        float sc = g1[ot * 64 + cc] * rsqrtf(v1[ot * 64 + cc] + 1e-5f);
        #pragma unroll
        for (int it = 0; it < 16; ++it) {
            int crow = it * 4 + rr;        // c_local
            w1ts[(size_t)(ct * 64 + crow) * CIN_ + ot * 64 + cc] = f2bf(ld65[cc][crow] * sc);
        }
        return;
    }
    // NCHW -> NHWC bf16
    const int bn = bid - 576;
    const int b = bn >> 4, c0 = (bn & 15) << 6;
    const float* src = fmap_in + ((size_t)b * CIN_ + c0) * HW_;
    #pragma unroll
    for (int it = 0; it < 49; ++it) {
        int idx = it * 256 + t;
        int ci = idx / 196;
        int hw = idx - ci * 196;
        ld[ci][hw] = src[idx];
    }
    __syncthreads();
    u16* dst = anhwc + (size_t)b * HW_ * CIN_ + c0;
    #pragma unroll
    for (int it = 0; it < 49; ++it) {
        int idx = it * 256 + t;
        int hw = idx >> 6, ci = idx & 63;
        dst[(size_t)hw * CIN_ + ci] = f2bf(ld[ci][hw]);
    }
}

// ---------------- prep: cfc[cls] = bfc + sum_bin (w_bin.bi2 + wG.bi1) ----------------
__global__ __launch_bounds__(256) void k_cfc(
    const u16* __restrict__ w_bin, const u16* __restrict__ wG,
    const float* __restrict__ g1, const float* __restrict__ b1,
    const float* __restrict__ m1, const float* __restrict__ v1,
    const float* __restrict__ g2, const float* __restrict__ b2,
    const float* __restrict__ m2, const float* __restrict__ v2,
    const float* __restrict__ bfc, float* __restrict__ cfc)
{
    __shared__ float ps[4];
    const int cls = blockIdx.x, t = threadIdx.x;
    float bi2 = b2[t] - m2[t] * (g2[t] * rsqrtf(v2[t] + 1e-5f));
    float s = 0.0f;
    #pragma unroll
    for (int bin = 0; bin < 9; ++bin)
        s += bf2f(w_bin[(cls * 9 + bin) * 256 + t]) * bi2;
    #pragma unroll
    for (int j = 0; j < 4; ++j) {
        int o = t + 256 * j;
        float bi1 = b1[o] - m1[o] * (g1[o] * rsqrtf(v1[o] + 1e-5f));
        #pragma unroll
        for (int bin = 0; bin < 9; ++bin)
            s += bf2f(wG[(size_t)(cls * 9 + bin) * CIN_ + o]) * bi1;
    }
    #pragma unroll
    for (int o = 32; o > 0; o >>= 1) s += __shfl_xor(s, o, 64);
    if ((t & 63) == 0) ps[t >> 6] = s;
    __syncthreads();
    if (t == 0) cfc[cls] = bfc[cls] + ps[0] + ps[1] + ps[2] + ps[3];
}

// ---------------- generic split-K GEMM: out[m][n] = sum_k A[m][k]*B[n][k], bf16 out --
// 512 thr = 2 x (4-wave 64x64 sub-GEMM over K/2). BK=64, reg-prefetch of next K-tile
// issued between barrier and MFMA (gemm1's proven structure), [64][72] LDS pitch.
__global__ __launch_bounds__(512) void k_gemm_sk(
    const u16* __restrict__ A, const u16* __restrict__ Bw, u16* __restrict__ outp,
    int N, int K)
{
    __shared__ u16 As[2][64][72];
    __shared__ u16 Bs[2][64][72];
    __shared__ float red[4096];
    const int row0 = blockIdx.y * 64, col0 = blockIdx.x * 64;
    const int t = threadIdx.x, kw = t >> 8, tt = t & 255;
    const int wave = tt >> 6, lane = tt & 63;
    const int wr = (wave >> 1) * 32, wc = (wave & 1) * 32;
    const int fr = lane & 15, fk = (lane >> 4) * 8;
    const int sr = tt >> 2, sk = (tt & 3) * 16;
    const int Kh = K >> 1;
    const int nkt = Kh >> 6;
    f32x4 acc[2][2] = {};
    const u16* Ap = A + (size_t)(row0 + sr) * K + kw * Kh + sk;
    const u16* Bp = Bw + (size_t)(col0 + sr) * K + kw * Kh + sk;
    uint4 a0 = *reinterpret_cast<const uint4*>(Ap);
    uint4 a1 = *reinterpret_cast<const uint4*>(Ap + 8);
    uint4 b0 = *reinterpret_cast<const uint4*>(Bp);
    uint4 b1 = *reinterpret_cast<const uint4*>(Bp + 8);
    for (int kt = 0; kt < nkt; ++kt) {
        *reinterpret_cast<uint4*>(&As[kw][sr][sk]) = a0;
        *reinterpret_cast<uint4*>(&As[kw][sr][sk + 8]) = a1;
        *reinterpret_cast<uint4*>(&Bs[kw][sr][sk]) = b0;
        *reinterpret_cast<uint4*>(&Bs[kw][sr][sk + 8]) = b1;
        __syncthreads();
        if (kt < nkt - 1) {
            const int k0 = (kt + 1) * 64;
            a0 = *reinterpret_cast<const uint4*>(Ap + k0);
            a1 = *reinterpret_cast<const uint4*>(Ap + k0 + 8);
            b0 = *reinterpret_cast<const uint4*>(Bp + k0);
            b1 = *reinterpret_cast<const uint4*>(Bp + k0 + 8);
        }
        #pragma unroll
        for (int kk = 0; kk < 2; ++kk) {
            const int ko = fk + kk * 32;
            bf16x8 af0 = *reinterpret_cast<bf16x8*>(&As[kw][wr + fr][ko]);
            bf16x8 af1 = *reinterpret_cast<bf16x8*>(&As[kw][wr + 16 + fr][ko]);
            bf16x8 bf0 = *reinterpret_cast<bf16x8*>(&Bs[kw][wc + fr][ko]);
            bf16x8 bf1 = *reinterpret_cast<bf16x8*>(&Bs[kw][wc + 16 + fr][ko]);
            acc[0][0] = __builtin_amdgcn_mfma_f32_16x16x32_bf16(af0, bf0, acc[0][0], 0, 0, 0);
            acc[0][1] = __builtin_amdgcn_mfma_f32_16x16x32_bf16(af0, bf1, acc[0][1], 0, 0, 0);
            acc[1][0] = __builtin_amdgcn_mfma_f32_16x16x32_bf16(af1, bf0, acc[1][0], 0, 0, 0);
            acc[1][1] = __builtin_amdgcn_mfma_f32_16x16x32_bf16(af1, bf1, acc[1][1], 0, 0, 0);
        }
        __syncthreads();
    }
    if (kw == 1) {
        #pragma unroll
        for (int mi = 0; mi < 2; ++mi)
            #pragma unroll
            for (int ni = 0; ni < 2; ++ni)
                #pragma unroll
                for (int rgi = 0; rgi < 4; ++rgi)
                    red[wave * 1024 + lane * 16 + (mi * 2 + ni) * 4 + rgi] = acc[mi][ni][rgi];
    }
    __syncthreads();
    if (kw == 0) {
        #pragma unroll
        for (int mi = 0; mi < 2; ++mi) {
            #pragma unroll
            for (int ni = 0; ni < 2; ++ni) {
                int col = col0 + wc + ni * 16 + fr;
                #pragma unroll
                for (int rgi = 0; rgi < 4; ++rgi) {
                    int row = row0 + wr + mi * 16 + (lane >> 4) * 4 + rgi;
                    float s = acc[mi][ni][rgi]
                            + red[wave * 1024 + lane * 16 + (mi * 2 + ni) * 4 + rgi];
                    outp[(size_t)row * N + col] = f2bf(s);
                }
            }
        }
    }
}

// ---------------- K3: roi pooling on bf16 G -> logits ----------------
__global__ __launch_bounds__(256) void k_roi_logits(
    const float* __restrict__ boxes, const u16* __restrict__ G,
    const float* __restrict__ cfc, float* __restrict__ out)
{
    __shared__ float sred[4][260];
    const int t = threadIdx.x, w = t >> 6, lane = t & 63;
    const int r = blockIdx.x * 4 + w;
    const int b = r / ROIS_;
    const float* bxp = boxes + (size_t)r * 4;
    float x1 = bxp[0], y1 = bxp[1];
    float rw = fmaxf(bxp[2] - x1, 1.0f), rh = fmaxf(bxp[3] - y1, 1.0f);
    float sx = rw * (1.0f / 3.0f), sy = rh * (1.0f / 3.0f);
    const float OFFS[6] = {0.25f, 0.75f, 1.25f, 1.75f, 2.25f, 2.75f};

    int xl[6], xh[6], yl[6], yh[6];
    float lx[6], hx[6], ly[6], hy[6];
    #pragma unroll
    for (int i = 0; i < 6; ++i) {
        float xx = fmaxf(x1 + OFFS[i] * sx, 0.0f);
        xl[i] = min((int)xx, 13); xh[i] = min(xl[i] + 1, 13);
        float xv = (xl[i] == 13) ? 13.0f : xx;
        lx[i] = xv - (float)xl[i]; hx[i] = 1.0f - lx[i];
        float yy = fmaxf(y1 + OFFS[i] * sy, 0.0f);
        yl[i] = min((int)yy, 13); yh[i] = min(yl[i] + 1, 13);
        float yv = (yl[i] == 13) ? 13.0f : yy;
        ly[i] = yv - (float)yl[i]; hy[i] = 1.0f - ly[i];
    }
    const int xc0 = min(xl[0], 8), yr0 = min(yl[0], 8);

    float WX[3][6], WY[3][6];
    #pragma unroll
    for (int bi = 0; bi < 3; ++bi)
        #pragma unroll
        for (int c = 0; c < 6; ++c) { WX[bi][c] = 0.0f; WY[bi][c] = 0.0f; }
    #pragma unroll
    for (int i = 0; i < 6; ++i) {
        const int bi = i >> 1;
        #pragma unroll
        for (int c = 0; c < 6; ++c) {
            WX[bi][c] += (xl[i] - xc0 == c ? hx[i] : 0.0f)
                       + (xh[i] - xc0 == c ? lx[i] : 0.0f);
            WY[bi][c] += (yl[i] - yr0 == c ? hy[i] : 0.0f)
                       + (yh[i] - yr0 == c ? ly[i] : 0.0f);
        }
    }

    int bxj[4], byj[4];
    #pragma unroll
    for (int j = 0; j < 4; ++j) {
        int cb = lane * 4 + j;
        int cls = cb / 9;
        int bin = cb - cls * 9;
        bxj[j] = bin % 3; byj[j] = bin / 3;
    }
    f32x4 wx4[6], wy4[6];
    #pragma unroll
    for (int q = 0; q < 6; ++q) {
        #pragma unroll
        for (int j = 0; j < 4; ++j) {
            wx4[q][j] = (bxj[j] == 0) ? WX[0][q] : ((bxj[j] == 1) ? WX[1][q] : WX[2][q]);
            wy4[q][j] = (byj[j] == 0) ? WY[0][q] : ((byj[j] == 1) ? WY[1][q] : WY[2][q]);
        }
    }

    const u16* base = G + ((size_t)b * HW_ + yr0 * 14 + xc0) * NCB_ + lane * 4;
    f32x4 acc = {};
    #pragma unroll
    for (int rr = 0; rr < 6; ++rr) {
        const u16* rp = base + rr * (14 * NCB_);
        f32x4 tmp = {};
        #pragma unroll
        for (int cc = 0; cc < 6; ++cc) {
            uint2 gu = *reinterpret_cast<const uint2*>(rp + cc * NCB_);
            f32x4 g;
            g[0] = bits2f(gu.x << 16); g[1] = bits2f(gu.x & 0xFFFF0000u);
            g[2] = bits2f(gu.y << 16); g[3] = bits2f(gu.y & 0xFFFF0000u);
            tmp += g * wx4[cc];
        }
        acc += tmp * wy4[rr];
    }
    acc *= 0.25f;
    #pragma unroll
    for (int j = 0; j < 4; ++j) sred[w][lane * 4 + j] = acc[j];
    __syncthreads();
    if (lane < NCLS_) {
        float s = cfc[lane];
        #pragma unroll
        for (int bin = 0; bin < 9; ++bin) s += sred[w][lane * 9 + bin];
        out[(size_t)r * NCLS_ + lane] = s;
    }
}

extern "C" void kernel_launch(void* const* d_in, const int* in_sizes, int n_in,
                              void* d_out, int out_size, void* d_ws, size_t ws_size,
                              hipStream_t stream) {
    const float* boxes   = (const float*)d_in[0];
    const float* fmap_in = (const float*)d_in[1];
    const float* w1 = (const float*)d_in[2];
    const float* g1 = (const float*)d_in[3];
    const float* b1 = (const float*)d_in[4];
    const float* m1 = (const float*)d_in[5];
    const float* v1 = (const float*)d_in[6];
    const float* w2 = (const float*)d_in[7];
    const float* g2 = (const float*)d_in[8];
    const float* b2 = (const float*)d_in[9];
    const float* m2 = (const float*)d_in[10];
    const float* v2 = (const float*)d_in[11];
    const float* wfc = (const float*)d_in[12];
    const float* bfc = (const float*)d_in[13];

    char* ws = (char*)d_ws;
    u16*   Anhwc = (u16*)(ws + 0);                   //  6,422,528 B
    u16*   G16   = (u16*)(ws + 6422528);             //  1,605,632 B
    u16*   w_bin = (u16*)(ws + 8028160);             //    131,072 B
    u16*   w2s   = (u16*)(ws + 8159232);             //    524,288 B
    u16*   w1ts  = (u16*)(ws + 8683520);             //  2,097,152 B
    u16*   wG    = (u16*)(ws + 10780672);            //    524,288 B
    u16*   Wtot  = (u16*)(ws + 11304960);            //    524,288 B
    float* cfc   = (float*)(ws + 11829248);          //        128 B

    hipLaunchKernelGGL(k_prep, dim3(832), dim3(256), 0, stream,
                       wfc, w_bin, w2, g2, v2, w2s, w1, g1, v1, w1ts, fmap_in, Anhwc);
    // wG[cb][o] = sum_cmid w_bin[cb][cmid] * w2s[o][cmid]   (M=256, N=1024, K=256)
    hipLaunchKernelGGL(k_gemm_sk, dim3(CIN_ / 64, NCB_ / 64), dim3(512), 0, stream,
                       w_bin, w2s, wG, CIN_, CMID_);
    // Wtot[cb][c] = sum_o wG[cb][o] * w1ts[c][o]            (M=256, N=1024, K=1024)
    hipLaunchKernelGGL(k_gemm_sk, dim3(CIN_ / 64, NCB_ / 64), dim3(512), 0, stream,
                       wG, w1ts, Wtot, CIN_, CIN_);
    hipLaunchKernelGGL(k_cfc, dim3(NCLS_), dim3(256), 0, stream,
                       w_bin, wG, g1, b1, m1, v1, g2, b2, m2, v2, bfc, cfc);
    // G16[m][cb] = sum_c Anhwc[m][c] * Wtot[cb][c]          (M=3136, N=256, K=1024)
    hipLaunchKernelGGL(k_gemm_sk, dim3(NCB_ / 64, M_ / 64), dim3(512), 0, stream,
                       Anhwc, Wtot, G16, NCB_, CIN_);
    hipLaunchKernelGGL(k_roi_logits, dim3(NROI_ / 4), dim3(256), 0, stream,
                       boxes, G16, cfc, (float*)d_out);
}

// Round 16
// 58.824 us; speedup vs baseline: 2.0500x; 1.1258x over previous
//
#include <hip/hip_runtime.h>
#include <hip/hip_bf16.h>
#include <math.h>

#define H_ 14
#define W_ 14
#define HW_ 196
#define CIN_ 1024
#define CMID_ 256
#define NCLS_ 27
#define NB_ 16
#define ROIS_ 980
#define M_ 3136
#define FEAT_ 2304
#define NROI_ (NB_ * ROIS_)   // 15680
#define NCB_ 256              // padded cb = cls*9+bin (243 real)

typedef unsigned short u16;
typedef __attribute__((ext_vector_type(8))) short bf16x8;
typedef __attribute__((ext_vector_type(4))) float f32x4;

__device__ __forceinline__ float bf2f(u16 u) {
    union { unsigned int i; float f; } x; x.i = ((unsigned int)u) << 16; return x.f;
}
__device__ __forceinline__ float bits2f(unsigned int u) {
    union { unsigned int i; float f; } x; x.i = u; return x.f;
}
__device__ __forceinline__ u16 f2bf(float f) {
    __hip_bfloat16 h = __float2bfloat16(f);
    return *reinterpret_cast<u16*>(&h);
}

// ---------------- merged prep ----------------
// blocks [0,256):   w_bin[cb][c] = wfc[cls][c*9+bin]                (bf16, pad cb>=243)
// blocks [256,320): w2s[o][cmid] = w2[cmid][o]*sc2[cmid]            (LDS transpose)
// blocks [320,576): w1ts[c][o]   = w1[o][c]*sc1[o]                  (LDS transpose)
// blocks [576,832): Anhwc[b][hw][c] = bf16(fmap_in[b][c][hw])       (LDS transpose)
// blocks [832,894): rw[roi][40]  = separable pooling weights WX[3][6],WY[3][6],basepix
__global__ __launch_bounds__(256) void k_prep(
    const float* __restrict__ wfc, u16* __restrict__ w_bin,
    const float* __restrict__ w2, const float* __restrict__ g2,
    const float* __restrict__ v2, u16* __restrict__ w2s,
    const float* __restrict__ w1, const float* __restrict__ g1,
    const float* __restrict__ v1, u16* __restrict__ w1ts,
    const float* __restrict__ fmap_in, u16* __restrict__ anhwc,
    const float* __restrict__ boxes, float* __restrict__ rw_out)
{
    __shared__ float ld[64][197];
    float (*ld65)[65] = (float(*)[65])&ld[0][0];
    const int bid = blockIdx.x, t = threadIdx.x;
    if (bid < 256) {                       // w_bin
        int idx = bid * 256 + t;
        int cb = idx >> 8, c = idx & 255;
        int cls = cb / 9, bin = cb - cls * 9;
        w_bin[idx] = f2bf((cb < 243) ? wfc[cls * FEAT_ + c * 9 + bin] : 0.0f);
        return;
    }
    if (bid < 320) {                       // w2s: in w2[256][1024] -> out [1024][256]
        const int b2id = bid - 256;
        const int kt = b2id & 15, ct = b2id >> 4;
        const int rr = t >> 6, cc = t & 63;
        #pragma unroll
        for (int it = 0; it < 16; ++it) {
            int row = it * 4 + rr;
            ld65[row][cc] = w2[(size_t)(ct * 64 + row) * CIN_ + kt * 64 + cc];
        }
        __syncthreads();
        float sc = g2[ct * 64 + cc] * rsqrtf(v2[ct * 64 + cc] + 1e-5f);
        #pragma unroll
        for (int it = 0; it < 16; ++it) {
            int krow = it * 4 + rr;
            w2s[(size_t)(kt * 64 + krow) * CMID_ + ct * 64 + cc] = f2bf(ld65[cc][krow] * sc);
        }
        return;
    }
    if (bid < 576) {                       // w1ts: in w1[1024 o][1024 c] -> out [c][o]*sc1[o]
        const int b1id = bid - 320;
        const int ot = b1id & 15, ct = b1id >> 4;
        const int rr = t >> 6, cc = t & 63;
        #pragma unroll
        for (int it = 0; it < 16; ++it) {
            int row = it * 4 + rr;         // o_local
            ld65[row][cc] = w1[(size_t)(ot * 64 + row) * CIN_ + ct * 64 + cc];
        }
        __syncthreads();
        float sc = g1[ot * 64 + cc] * rsqrtf(v1[ot * 64 + cc] + 1e-5f);
        #pragma unroll
        for (int it = 0; it < 16; ++it) {
            int crow = it * 4 + rr;        // c_local
            w1ts[(size_t)(ct * 64 + crow) * CIN_ + ot * 64 + cc] = f2bf(ld65[cc][crow] * sc);
        }
        return;
    }
    if (bid < 832) {                       // NCHW -> NHWC bf16
        const int bn = bid - 576;
        const int b = bn >> 4, c0 = (bn & 15) << 6;
        const float* src = fmap_in + ((size_t)b * CIN_ + c0) * HW_;
        #pragma unroll
        for (int it = 0; it < 49; ++it) {
            int idx = it * 256 + t;
            int ci = idx / 196;
            int hw = idx - ci * 196;
            ld[ci][hw] = src[idx];
        }
        __syncthreads();
        u16* dst = anhwc + (size_t)b * HW_ * CIN_ + c0;
        #pragma unroll
        for (int it = 0; it < 49; ++it) {
            int idx = it * 256 + t;
            int hw = idx >> 6, ci = idx & 63;
            dst[(size_t)hw * CIN_ + ci] = f2bf(ld[ci][hw]);
        }
        return;
    }
    // per-roi separable pooling weights (thread = roi)
    const int r = (bid - 832) * 256 + t;
    if (r >= NROI_) return;
    const float* bxp = boxes + (size_t)r * 4;
    float x1 = bxp[0], y1 = bxp[1];
    float rwd = fmaxf(bxp[2] - x1, 1.0f), rhd = fmaxf(bxp[3] - y1, 1.0f);
    float sx = rwd * (1.0f / 3.0f), sy = rhd * (1.0f / 3.0f);
    const float OFFS[6] = {0.25f, 0.75f, 1.25f, 1.75f, 2.25f, 2.75f};
    int xl[6], xh[6], yl[6], yh[6];
    float lx[6], hx[6], ly[6], hy[6];
    #pragma unroll
    for (int i = 0; i < 6; ++i) {
        float xx = fmaxf(x1 + OFFS[i] * sx, 0.0f);
        xl[i] = min((int)xx, 13); xh[i] = min(xl[i] + 1, 13);
        float xv = (xl[i] == 13) ? 13.0f : xx;
        lx[i] = xv - (float)xl[i]; hx[i] = 1.0f - lx[i];
        float yy = fmaxf(y1 + OFFS[i] * sy, 0.0f);
        yl[i] = min((int)yy, 13); yh[i] = min(yl[i] + 1, 13);
        float yv = (yl[i] == 13) ? 13.0f : yy;
        ly[i] = yv - (float)yl[i]; hy[i] = 1.0f - ly[i];
    }
    const int xc0 = min(xl[0], 8), yr0 = min(yl[0], 8);
    float WX[3][6], WY[3][6];
    #pragma unroll
    for (int bi = 0; bi < 3; ++bi)
        #pragma unroll
        for (int c = 0; c < 6; ++c) { WX[bi][c] = 0.0f; WY[bi][c] = 0.0f; }
    #pragma unroll
    for (int i = 0; i < 6; ++i) {
        const int bi = i >> 1;
        #pragma unroll
        for (int c = 0; c < 6; ++c) {
            WX[bi][c] += (xl[i] - xc0 == c ? hx[i] : 0.0f)
                       + (xh[i] - xc0 == c ? lx[i] : 0.0f);
            WY[bi][c] += (yl[i] - yr0 == c ? hy[i] : 0.0f)
                       + (yh[i] - yr0 == c ? ly[i] : 0.0f);
        }
    }
    float* ro = rw_out + (size_t)r * 40;
    #pragma unroll
    for (int bi = 0; bi < 3; ++bi)
        #pragma unroll
        for (int c = 0; c < 6; ++c) { ro[bi * 6 + c] = WX[bi][c]; ro[18 + bi * 6 + c] = WY[bi][c]; }
    ro[36] = (float)(yr0 * 14 + xc0);     // window base pixel
}

// ---------------- generic split-K GEMM + (bid>=nct) cfc branch --------------
// 512 thr = 2 x (4-wave 64x64 sub-GEMM over K/2). BK=64, reg-prefetch (R9 structure).
template<bool WITH_CFC>
__global__ __launch_bounds__(512) void k_gemm_sk(
    const u16* __restrict__ A, const u16* __restrict__ Bw, u16* __restrict__ outp,
    int N, int K, int nct,
    const u16* __restrict__ w_bin, const u16* __restrict__ wG,
    const float* __restrict__ g1, const float* __restrict__ b1,
    const float* __restrict__ m1, const float* __restrict__ v1,
    const float* __restrict__ g2, const float* __restrict__ b2,
    const float* __restrict__ m2, const float* __restrict__ v2,
    const float* __restrict__ bfc, float* __restrict__ cfc)
{
    __shared__ u16 As[2][64][72];
    __shared__ u16 Bs[2][64][72];
    __shared__ float red[4096];
    const int bid = blockIdx.x;
    if (WITH_CFC && bid >= nct) {
        __shared__ float ps[4];
        const int cls = bid - nct, t = threadIdx.x;
        if (t < 256) {
            float bi2 = b2[t] - m2[t] * (g2[t] * rsqrtf(v2[t] + 1e-5f));
            float s = 0.0f;
            #pragma unroll
            for (int bin = 0; bin < 9; ++bin)
                s += bf2f(w_bin[(cls * 9 + bin) * 256 + t]) * bi2;
            #pragma unroll
            for (int j = 0; j < 4; ++j) {
                int o = t + 256 * j;
                float bi1 = b1[o] - m1[o] * (g1[o] * rsqrtf(v1[o] + 1e-5f));
                #pragma unroll
                for (int bin = 0; bin < 9; ++bin)
                    s += bf2f(wG[(size_t)(cls * 9 + bin) * CIN_ + o]) * bi1;
            }
            #pragma unroll
            for (int o = 32; o > 0; o >>= 1) s += __shfl_xor(s, o, 64);
            if ((t & 63) == 0) ps[t >> 6] = s;
        }
        __syncthreads();
        if (threadIdx.x == 0) cfc[cls] = bfc[cls] + ps[0] + ps[1] + ps[2] + ps[3];
        return;
    }
    const int colt = bid % (N >> 6), rowt = bid / (N >> 6);
    const int row0 = rowt * 64, col0 = colt * 64;
    const int t = threadIdx.x, kw = t >> 8, tt = t & 255;
    const int wave = tt >> 6, lane = tt & 63;
    const int wr = (wave >> 1) * 32, wc = (wave & 1) * 32;
    const int fr = lane & 15, fk = (lane >> 4) * 8;
    const int sr = tt >> 2, sk = (tt & 3) * 16;
    const int Kh = K >> 1;
    const int nkt = Kh >> 6;
    f32x4 acc[2][2] = {};
    const u16* Ap = A + (size_t)(row0 + sr) * K + kw * Kh + sk;
    const u16* Bp = Bw + (size_t)(col0 + sr) * K + kw * Kh + sk;
    uint4 pa0 = *reinterpret_cast<const uint4*>(Ap);
    uint4 pa1 = *reinterpret_cast<const uint4*>(Ap + 8);
    uint4 pb0 = *reinterpret_cast<const uint4*>(Bp);
    uint4 pb1 = *reinterpret_cast<const uint4*>(Bp + 8);
    for (int kt = 0; kt < nkt; ++kt) {
        *reinterpret_cast<uint4*>(&As[kw][sr][sk]) = pa0;
        *reinterpret_cast<uint4*>(&As[kw][sr][sk + 8]) = pa1;
        *reinterpret_cast<uint4*>(&Bs[kw][sr][sk]) = pb0;
        *reinterpret_cast<uint4*>(&Bs[kw][sr][sk + 8]) = pb1;
        __syncthreads();
        if (kt < nkt - 1) {
            const int k0 = (kt + 1) * 64;
            pa0 = *reinterpret_cast<const uint4*>(Ap + k0);
            pa1 = *reinterpret_cast<const uint4*>(Ap + k0 + 8);
            pb0 = *reinterpret_cast<const uint4*>(Bp + k0);
            pb1 = *reinterpret_cast<const uint4*>(Bp + k0 + 8);
        }
        #pragma unroll
        for (int kk = 0; kk < 2; ++kk) {
            const int ko = fk + kk * 32;
            bf16x8 af0 = *reinterpret_cast<bf16x8*>(&As[kw][wr + fr][ko]);
            bf16x8 af1 = *reinterpret_cast<bf16x8*>(&As[kw][wr + 16 + fr][ko]);
            bf16x8 bf0 = *reinterpret_cast<bf16x8*>(&Bs[kw][wc + fr][ko]);
            bf16x8 bf1 = *reinterpret_cast<bf16x8*>(&Bs[kw][wc + 16 + fr][ko]);
            acc[0][0] = __builtin_amdgcn_mfma_f32_16x16x32_bf16(af0, bf0, acc[0][0], 0, 0, 0);
            acc[0][1] = __builtin_amdgcn_mfma_f32_16x16x32_bf16(af0, bf1, acc[0][1], 0, 0, 0);
            acc[1][0] = __builtin_amdgcn_mfma_f32_16x16x32_bf16(af1, bf0, acc[1][0], 0, 0, 0);
            acc[1][1] = __builtin_amdgcn_mfma_f32_16x16x32_bf16(af1, bf1, acc[1][1], 0, 0, 0);
        }
        __syncthreads();
    }
    if (kw == 1) {
        #pragma unroll
        for (int mi = 0; mi < 2; ++mi)
            #pragma unroll
            for (int ni = 0; ni < 2; ++ni)
                #pragma unroll
                for (int rgi = 0; rgi < 4; ++rgi)
                    red[wave * 1024 + lane * 16 + (mi * 2 + ni) * 4 + rgi] = acc[mi][ni][rgi];
    }
    __syncthreads();
    if (kw == 0) {
        #pragma unroll
        for (int mi = 0; mi < 2; ++mi) {
            #pragma unroll
            for (int ni = 0; ni < 2; ++ni) {
                int col = col0 + wc + ni * 16 + fr;
                #pragma unroll
                for (int rgi = 0; rgi < 4; ++rgi) {
                    int row = row0 + wr + mi * 16 + (lane >> 4) * 4 + rgi;
                    float s = acc[mi][ni][rgi]
                            + red[wave * 1024 + lane * 16 + (mi * 2 + ni) * 4 + rgi];
                    outp[(size_t)row * N + col] = f2bf(s);
                }
            }
        }
    }
}

// ---------------- K3: roi pooling on bf16 G (precomputed weights) -> logits ----------
__global__ __launch_bounds__(256) void k_roi_logits(
    const float* __restrict__ rw, const u16* __restrict__ G,
    const float* __restrict__ cfc, float* __restrict__ out)
{
    __shared__ float sred[4][260];
    const int t = threadIdx.x, w = t >> 6, lane = t & 63;
    const int r = blockIdx.x * 4 + w;
    const int b = r / ROIS_;
    const float* rwp = rw + (size_t)r * 40;
    float WX[3][6], WY[3][6];
    #pragma unroll
    for (int q = 0; q < 9; ++q) {
        f32x4 v = *reinterpret_cast<const f32x4*>(rwp + q * 4);
        #pragma unroll
        for (int j = 0; j < 4; ++j) {
            int idx = q * 4 + j;                       // 0..35
            if (idx < 18) WX[idx / 6][idx % 6] = v[j];
            else          WY[(idx - 18) / 6][(idx - 18) % 6] = v[j];
        }
    }
    const int basepix = (int)rwp[36];

    int bxj[4], byj[4];
    #pragma unroll
    for (int j = 0; j < 4; ++j) {
        int cb = lane * 4 + j;
        int cls = cb / 9;
        int bin = cb - cls * 9;
        bxj[j] = bin % 3; byj[j] = bin / 3;
    }
    f32x4 wx4[6], wy4[6];
    #pragma unroll
    for (int q = 0; q < 6; ++q) {
        #pragma unroll
        for (int j = 0; j < 4; ++j) {
            wx4[q][j] = (bxj[j] == 0) ? WX[0][q] : ((bxj[j] == 1) ? WX[1][q] : WX[2][q]);
            wy4[q][j] = (byj[j] == 0) ? WY[0][q] : ((byj[j] == 1) ? WY[1][q] : WY[2][q]);
        }
    }

    const u16* base = G + ((size_t)b * HW_ + basepix) * NCB_ + lane * 4;
    f32x4 acc = {};
    #pragma unroll
    for (int rr = 0; rr < 6; ++rr) {
        const u16* rp = base + rr * (14 * NCB_);
        f32x4 tmp = {};
        #pragma unroll
        for (int cc = 0; cc < 6; ++cc) {
            uint2 gu = *reinterpret_cast<const uint2*>(rp + cc * NCB_);
            f32x4 g;
            g[0] = bits2f(gu.x << 16); g[1] = bits2f(gu.x & 0xFFFF0000u);
            g[2] = bits2f(gu.y << 16); g[3] = bits2f(gu.y & 0xFFFF0000u);
            tmp += g * wx4[cc];
        }
        acc += tmp * wy4[rr];
    }
    acc *= 0.25f;
    #pragma unroll
    for (int j = 0; j < 4; ++j) sred[w][lane * 4 + j] = acc[j];
    __syncthreads();
    if (lane < NCLS_) {
        float s = cfc[lane];
        #pragma unroll
        for (int bin = 0; bin < 9; ++bin) s += sred[w][lane * 9 + bin];
        out[(size_t)r * NCLS_ + lane] = s;
    }
}

extern "C" void kernel_launch(void* const* d_in, const int* in_sizes, int n_in,
                              void* d_out, int out_size, void* d_ws, size_t ws_size,
                              hipStream_t stream) {
    const float* boxes   = (const float*)d_in[0];
    const float* fmap_in = (const float*)d_in[1];
    const float* w1 = (const float*)d_in[2];
    const float* g1 = (const float*)d_in[3];
    const float* b1 = (const float*)d_in[4];
    const float* m1 = (const float*)d_in[5];
    const float* v1 = (const float*)d_in[6];
    const float* w2 = (const float*)d_in[7];
    const float* g2 = (const float*)d_in[8];
    const float* b2 = (const float*)d_in[9];
    const float* m2 = (const float*)d_in[10];
    const float* v2 = (const float*)d_in[11];
    const float* wfc = (const float*)d_in[12];
    const float* bfc = (const float*)d_in[13];

    char* ws = (char*)d_ws;
    u16*   Anhwc = (u16*)(ws + 0);                   //  6,422,528 B
    u16*   G16   = (u16*)(ws + 6422528);             //  1,605,632 B
    u16*   w_bin = (u16*)(ws + 8028160);             //    131,072 B
    u16*   w2s   = (u16*)(ws + 8159232);             //    524,288 B
    u16*   w1ts  = (u16*)(ws + 8683520);             //  2,097,152 B
    u16*   wG    = (u16*)(ws + 10780672);            //    524,288 B
    u16*   Wtot  = (u16*)(ws + 11304960);            //    524,288 B
    float* cfc   = (float*)(ws + 11829248);          //        128 B
    float* rw    = (float*)(ws + 11829376);          //  2,508,800 B (15680*40*4)

    hipLaunchKernelGGL(k_prep, dim3(832 + 62), dim3(256), 0, stream,
                       wfc, w_bin, w2, g2, v2, w2s, w1, g1, v1, w1ts, fmap_in, Anhwc,
                       boxes, rw);
    // wG[cb][o] = sum_cmid w_bin[cb][cmid] * w2s[o][cmid]   (M=256, N=1024, K=256)
    hipLaunchKernelGGL((k_gemm_sk<false>), dim3(64), dim3(512), 0, stream,
                       w_bin, w2s, wG, CIN_, CMID_, 64,
                       nullptr, nullptr, nullptr, nullptr, nullptr, nullptr,
                       nullptr, nullptr, nullptr, nullptr, nullptr, nullptr);
    // Wtot[cb][c] = sum_o wG[cb][o] * w1ts[c][o]  (64 blocks) + cfc (27 blocks)
    hipLaunchKernelGGL((k_gemm_sk<true>), dim3(64 + NCLS_), dim3(512), 0, stream,
                       wG, w1ts, Wtot, CIN_, CIN_, 64,
                       w_bin, wG, g1, b1, m1, v1, g2, b2, m2, v2, bfc, cfc);
    // G16[m][cb] = sum_c Anhwc[m][c] * Wtot[cb][c]          (M=3136, N=256, K=1024)
    hipLaunchKernelGGL((k_gemm_sk<false>), dim3(4 * 49), dim3(512), 0, stream,
                       Anhwc, Wtot, G16, NCB_, CIN_, 196,
                       nullptr, nullptr, nullptr, nullptr, nullptr, nullptr,
                       nullptr, nullptr, nullptr, nullptr, nullptr, nullptr);
    hipLaunchKernelGGL(k_roi_logits, dim3(NROI_ / 4), dim3(256), 0, stream,
                       rw, G16, cfc, (float*)d_out);
}